// Round 5
// baseline (530.605 us; speedup 1.0000x reference)
//
#include <hip/hip_runtime.h>
#include <hip/hip_bf16.h>
#include <stdint.h>

#define NN 65536
#define NE 1048576
#define E2 (NE + NN)      // edges + self loops = 1,114,112 = 8704*128
#define HID 128
#define LP 136            // padded LDS row pitch (fp16 elems) for node-kernel tiles
#define RMAX 13           // max runs in LDS run-table (overflow -> global atomics)
#define TP 129            // run-table stride in words
#define TABW 1680         // ceil(RMAX*TP/4)*4 words
#define ENC_NEG 0x007FFFFFu   // encf(-inf)

typedef _Float16 h8v __attribute__((ext_vector_type(8)));
typedef __fp16 fp16x2 __attribute__((ext_vector_type(2)));
typedef __attribute__((ext_vector_type(4))) float f32x4;

__device__ __forceinline__ uint32_t pkh(float a, float b){
    union { fp16x2 h; uint32_t u; } v;
    v.h = __builtin_amdgcn_cvt_pkrtz(a, b);
    return v.u;
}
// monotone float->uint encoding for unsigned atomicMax (branchless)
__device__ __forceinline__ uint32_t encf(float x){
    union { float f; uint32_t u; } v; v.f = x;
    return v.u ^ (uint32_t)(((int32_t)v.u >> 31) | 0x80000000);
}
__device__ __forceinline__ float decf(uint32_t u){
    union { uint32_t u; float f; } v;
    v.u = u ^ (uint32_t)(~((int32_t)u >> 31) | 0x80000000);
    return v.f;
}

// direct global->LDS DMA, 16B per lane (dest = wave-uniform base + lane*16)
__device__ __forceinline__ void gl_lds16(const _Float16* g, _Float16* l){
    __builtin_amdgcn_global_load_lds(
        (const __attribute__((address_space(1))) uint32_t*)g,
        (__attribute__((address_space(3))) uint32_t*)l, 16, 0, 0);
}

// ---- stage one 64-elem half-row into LDS (padded LP layout) ----
__device__ __forceinline__ void stage_cvt(const float* g, _Float16* l){
    const float4* gs = (const float4*)g; uint4* ls = (uint4*)l;
    #pragma unroll
    for (int j = 0; j < 8; j++){
        float4 f0 = gs[2*j], f1 = gs[2*j+1];
        uint4 o; o.x = pkh(f0.x, f0.y); o.y = pkh(f0.z, f0.w);
        o.z = pkh(f1.x, f1.y); o.w = pkh(f1.z, f1.w);
        ls[j] = o;
    }
}

// 128x128x128 fp16 GEMM: A from padded LDS tile, B (weights) DIRECT FROM GLOBAL.
// Weights are 32 KB shared by all blocks -> L1/L2 resident; fragment read is the
// same 16B-aligned contiguous pattern as the old LDS read. Removes Ws staging,
// halves node-kernel LDS (69.6 -> 34.8 KB) -> occupancy 2 -> 3-4 blocks/CU.
__device__ __forceinline__ void gemm_tile_g(const _Float16* Ts, const _Float16* __restrict__ Wg,
                                            f32x4 (&acc)[2][8], int wv, int lq, int quad){
    #pragma unroll
    for (int k0 = 0; k0 < 128; k0 += 32){
        h8v af[2], bfr[8];
        #pragma unroll
        for (int rt = 0; rt < 2; rt++)
            af[rt] = *(const h8v*)(Ts + (wv*32 + rt*16 + lq)*LP + k0 + quad*8);
        #pragma unroll
        for (int ct = 0; ct < 8; ct++)
            bfr[ct] = *(const h8v*)(Wg + (ct*16 + lq)*HID + k0 + quad*8);
        #pragma unroll
        for (int rt = 0; rt < 2; rt++)
            #pragma unroll
            for (int ct = 0; ct < 8; ct++)
                acc[rt][ct] = __builtin_amdgcn_mfma_f32_16x16x32_f16(
                                  af[rt], bfr[ct], acc[rt][ct], 0, 0, 0);
    }
}

__device__ __forceinline__ void zero_acc(f32x4 (&acc)[2][8]){
    #pragma unroll
    for (int a = 0; a < 2; a++)
        #pragma unroll
        for (int b = 0; b < 8; b++)
            acc[a][b] = (f32x4){0.f, 0.f, 0.f, 0.f};
}

// ---------------- prep: weight transposes + cnt init + folded bias ----------------
struct WT { const float* s[10]; _Float16* d[10]; };
__global__ void k_prep(WT w, uint32_t* cnt,
                       const float* lb2_0, const float* gw1_0, const float* gb1_0,
                       const float* lb2_1, const float* gw1_1, const float* gb1_1,
                       float* c1p){
    int b = blockIdx.x;
    if (b < 640){
        int m = b >> 6;
        int t = (b & 63) * 256 + threadIdx.x;
        int n = t >> 7, k = t & 127;
        w.d[m][n*128 + k] = (_Float16)w.s[m][k*128 + n];
    } else if (b < 896){
        cnt[(b - 640)*256 + threadIdx.x] = 1u;        // self-loop pre-counted
    } else {
        // c1'[l][j] = gb1[j] + sum_k lb2[k]*gw1[k][j]   (folds b2 out of k_edge)
        int l = b - 896;
        int j = threadIdx.x;
        if (j < 128){
            const float* lb2 = l ? lb2_1 : lb2_0;
            const float* gw1 = l ? gw1_1 : gw1_0;
            float s = (l ? gb1_1 : gb1_0)[j];
            for (int k = 0; k < 128; k++) s += lb2[k] * gw1[k*128 + j];
            c1p[l*128 + j] = s;
        }
    }
}
__global__ void k_hist(const int* __restrict__ ei, uint32_t* cnt){
    int e = blockIdx.x * 256 + threadIdx.x;
    if (e < NE) atomicAdd(&cnt[ei[NE + e]], 1u);
}
__global__ void k_scan1(const uint32_t* __restrict__ cnt, uint32_t* __restrict__ bsum){
    __shared__ uint32_t ps[256];
    int t = threadIdx.x;
    ps[t] = cnt[blockIdx.x*256 + t]; __syncthreads();
    for (int off = 128; off > 0; off >>= 1){
        if (t < off) ps[t] += ps[t + off];
        __syncthreads();
    }
    if (t == 0) bsum[blockIdx.x] = ps[0];
}
__global__ void k_scan2(const uint32_t* __restrict__ bsum, uint32_t* __restrict__ bofs){
    __shared__ uint32_t ps[256];
    int t = threadIdx.x;
    uint32_t v = bsum[t];
    ps[t] = v; __syncthreads();
    for (int off = 1; off < 256; off <<= 1){
        uint32_t u = (t >= off) ? ps[t - off] : 0u;
        __syncthreads();
        ps[t] += u;
        __syncthreads();
    }
    bofs[t] = ps[t] - v;
}
__global__ void k_scan3(const uint32_t* __restrict__ cnt, const uint32_t* __restrict__ bofs,
                        uint32_t* __restrict__ cur){
    __shared__ uint32_t ps[256];
    int t = threadIdx.x, i = blockIdx.x*256 + t;
    uint32_t v = cnt[i];
    ps[t] = v; __syncthreads();
    for (int off = 1; off < 256; off <<= 1){
        uint32_t u = (t >= off) ? ps[t - off] : 0u;
        __syncthreads();
        ps[t] += u;
        __syncthreads();
    }
    cur[i] = bofs[blockIdx.x] + ps[t] - v;
}
__global__ void k_scatter(const int* __restrict__ ei, uint32_t* cur,
                          uint2* __restrict__ sedge){
    int e = blockIdx.x * 256 + threadIdx.x;
    if (e >= E2) return;
    uint32_t s, d;
    if (e < NE){ s = (uint32_t)ei[e]; d = (uint32_t)ei[NE + e]; }
    else { s = d = (uint32_t)(e - NE); }
    uint32_t p = atomicAdd(&cur[d], 1u);
    sedge[p] = make_uint2(s, d);
}

// ---------------- k_ab3: B1 = pos@W1b1 ; B0 = pos@W1b0 ; A0 = x@W1a0 + B0 + b1_0 ----
// R5: single accumulator (B1 first, then B0 kept live into the A-accumulation) ->
// 64 AGPRs freed -> (256,3). Weights direct-from-global (no Ws) -> LDS 34.8 KB.
// 3 barriers (was 5). Also inits agg rows to enc(-inf).
__launch_bounds__(256, 3)
__global__ void k_ab3(const float* __restrict__ x, const float* __restrict__ pos,
                      const _Float16* __restrict__ w1aT0, const _Float16* __restrict__ w1bT0,
                      const _Float16* __restrict__ w1bT1, const float* __restrict__ lb1_0,
                      _Float16* __restrict__ Ah, _Float16* __restrict__ Bh0,
                      _Float16* __restrict__ Bh1, uint32_t* __restrict__ agg){
    __shared__ _Float16 Ts[128*LP];
    __shared__ float b1s[128];
    const int tid = threadIdx.x;
    const int node0 = blockIdx.x * 128;
    if (tid < 128) b1s[tid] = lb1_0[tid];

    {   // init agg for this node range
        uint4* ap = (uint4*)(agg + (size_t)node0 * HID);
        uint4 v = make_uint4(ENC_NEG, ENC_NEG, ENC_NEG, ENC_NEG);
        #pragma unroll
        for (int i = 0; i < 16; i++) ap[tid + i*256] = v;
    }

    const int row = tid >> 1, half = tid & 1;
    stage_cvt(pos + (size_t)(node0 + row)*HID + half*64, Ts + row*LP + half*64);
    __syncthreads();                                   // bar1: pos tile ready

    const int wv = tid >> 6, lane = tid & 63, lq = lane & 15, quad = lane >> 4;
    f32x4 acc[2][8];
    zero_acc(acc);
    gemm_tile_g(Ts, w1bT1, acc, wv, lq, quad);         // acc = pos @ W1b1
    #pragma unroll
    for (int rt = 0; rt < 2; rt++)
        #pragma unroll
        for (int ct = 0; ct < 8; ct++)
            #pragma unroll
            for (int rg = 0; rg < 4; rg++){
                int r = node0 + wv*32 + rt*16 + quad*4 + rg;
                int c = ct*16 + lq;
                Bh1[(size_t)r*HID + c] = (_Float16)acc[rt][ct][rg];
            }
    zero_acc(acc);
    gemm_tile_g(Ts, w1bT0, acc, wv, lq, quad);         // acc = pos @ W1b0 (kept)
    #pragma unroll
    for (int rt = 0; rt < 2; rt++)
        #pragma unroll
        for (int ct = 0; ct < 8; ct++)
            #pragma unroll
            for (int rg = 0; rg < 4; rg++){
                int r = node0 + wv*32 + rt*16 + quad*4 + rg;
                int c = ct*16 + lq;
                Bh0[(size_t)r*HID + c] = (_Float16)acc[rt][ct][rg];
            }
    __syncthreads();                                   // bar2: pos readers done
    stage_cvt(x + (size_t)(node0 + row)*HID + half*64, Ts + row*LP + half*64);
    __syncthreads();                                   // bar3: x tile ready

    gemm_tile_g(Ts, w1aT0, acc, wv, lq, quad);         // acc += x @ W1a0

    #pragma unroll
    for (int rt = 0; rt < 2; rt++)
        #pragma unroll
        for (int ct = 0; ct < 8; ct++)
            #pragma unroll
            for (int rg = 0; rg < 4; rg++){
                int r = node0 + wv*32 + rt*16 + quad*4 + rg;
                int c = ct*16 + lq;
                Ah[(size_t)r*HID + c] = (_Float16)(acc[rt][ct][rg] + b1s[c]);
            }
}

// -------- edge kernel: agg[dst] = max over edges of relu(A[src]-B[dst]) @ W2 --------
// R4 structure (proven): 2 barriers, DMA-staged W2, per-lane edge loads, own-region
// run-table; 4 blocks/CU (LDS 40448, 128 unified regs).
__launch_bounds__(256, 4)
__global__ void k_edge(const uint2* __restrict__ sedge,
                       const _Float16* __restrict__ Ah, const _Float16* __restrict__ Bh,
                       const _Float16* __restrict__ w2T,
                       uint32_t* __restrict__ agg){
    __shared__ _Float16 Ws[128*128];                 // 32768 B, swizzled W2
    __shared__ __align__(16) uint32_t tab[TABW];     // 6720 B run-table (own region)
    __shared__ int ds_s[128];
    __shared__ unsigned long long masks_s[2];
    __shared__ int run_dst_s[RMAX];
    const int tid = threadIdx.x;
    const int bid = blockIdx.x;
    const int lb  = (bid & 7) * (E2/128/8) + (bid >> 3);   // XCD swizzle
    const int e0 = lb * 128;
    const int wv = tid >> 6, lane = tid & 63, lq = lane & 15, quad = lane >> 4;
    const int r0 = wv*32 + lq, r1 = r0 + 16;

    // ---- edge loads first (oldest in vmem FIFO -> cheap counted wait) ----
    const uint2 ea = sedge[e0 + r0];
    const uint2 eb = sedge[e0 + r1];
    int d_cur = 0;
    if (tid < 128) d_cur = (int)sedge[e0 + tid].y;

    // ---- W2 global->LDS DMA: linear dest, inverse-swizzled source ----
    #pragma unroll
    for (int rnd = 0; rnd < 8; rnd++){
        int g = rnd*256 + wv*64 + lane;              // 16B chunk id 0..2047
        int r = g >> 4, kc = g & 15;
        gl_lds16(w2T + r*HID + ((kc ^ (r & 15)) << 3),
                 Ws + rnd*2048 + wv*512);
    }

    // gathers: issue ASAP; drain at barrier1 under DMA + LDS bookkeeping
    const _Float16* a0p = Ah + (size_t)ea.x*HID + quad*8;
    const _Float16* a1p = Ah + (size_t)eb.x*HID + quad*8;
    const _Float16* b0p = Bh + (size_t)ea.y*HID + quad*8;
    const _Float16* b1p = Bh + (size_t)eb.y*HID + quad*8;
    h8v A0[4], A1[4], B0[4], B1[4];
    #pragma unroll
    for (int i = 0; i < 4; i++){
        A0[i] = *(const h8v*)(a0p + 32*i);
        A1[i] = *(const h8v*)(a1p + 32*i);
        B0[i] = *(const h8v*)(b0p + 32*i);
        B1[i] = *(const h8v*)(b1p + 32*i);
    }

    // boundary flags: d_prev via in-wave shuffles (no extra global loads).
    // lanes with (r1==63) hold sedge[e0+63] in eb -> shfl lane 15 serves tid 64.
    bool flag = false;
    if (tid < 128){
        ds_s[tid] = d_cur;
        int d_up  = __shfl_up(d_cur, 1);
        int d_b63 = __shfl((int)eb.y, 15);
        if (tid & 63) flag = (d_cur != d_up);
        else          flag = (tid == 0) ? true : (d_cur != d_b63);
        unsigned long long m = __ballot(flag);
        if ((tid & 63) == 0) masks_s[tid >> 6] = m;
    }
    {   // init run-table (TABW/4 = 420 uint4)
        uint4* t4 = (uint4*)tab;
        const uint4 vneg = make_uint4(ENC_NEG, ENC_NEG, ENC_NEG, ENC_NEG);
        #pragma unroll
        for (int i = 0; i < 2; i++){
            int idx = tid + i*256;
            if (idx < TABW/4) t4[idx] = vneg;
        }
    }
    __syncthreads();                            // barrier1: Ws/ds_s/masks/tab ready

    const unsigned long long m0 = masks_s[0], m1 = masks_s[1];
    const int c0 = __popcll(m0);
    const int nruns = c0 + __popcll(m1);

    // boundary threads record their run's dst (read post-barrier2 only)
    if (flag){
        int r;
        if (tid < 64) r = __popcll(m0 & ((2ull << tid) - 1)) - 1;
        else          r = c0 + __popcll(m1 & ((2ull << (tid-64)) - 1)) - 1;
        if (r < RMAX) run_dst_s[r] = d_cur;
    }

    f32x4 acc[2][8];
    zero_acc(acc);

    const h8v zero8 = (h8v)(_Float16)0;
    #pragma unroll
    for (int i = 0; i < 4; i++){
        h8v a0 = __builtin_elementwise_max(A0[i] - B0[i], zero8);
        h8v a1 = __builtin_elementwise_max(A1[i] - B1[i], zero8);
        const int kcb = i*4;
        #pragma unroll
        for (int ct = 0; ct < 8; ct++){
            h8v b = *(const h8v*)(Ws + (ct*16 + lq)*128 + (((kcb + quad) ^ lq) << 3));
            acc[0][ct] = __builtin_amdgcn_mfma_f32_16x16x32_f16(a0, b, acc[0][ct], 0, 0, 0);
            acc[1][ct] = __builtin_amdgcn_mfma_f32_16x16x32_f16(a1, b, acc[1][ct], 0, 0, 0);
        }
    }

    // flush acc -> run-table (tab does not alias Ws: no barrier needed)
    #pragma unroll
    for (int rt = 0; rt < 2; rt++){
        const int rb = wv*32 + rt*16 + quad*4;
        int rid[4];
        #pragma unroll
        for (int i = 0; i < 4; i++){
            int r = rb + i;
            if (r < 64) rid[i] = __popcll(m0 & ((2ull << r) - 1)) - 1;
            else        rid[i] = c0 + __popcll(m1 & ((2ull << (r-64)) - 1)) - 1;
        }
        const bool b01 = rid[1] != rid[0];
        const bool b12 = rid[2] != rid[1];
        const bool b23 = rid[3] != rid[2];
        #pragma unroll
        for (int ct = 0; ct < 8; ct++){
            const int c = ct*16 + lq;
            float v0 = acc[rt][ct][0], v1 = acc[rt][ct][1];
            float v2 = acc[rt][ct][2], v3 = acc[rt][ct][3];
            #define FLUSH(ID, R, V) do{ uint32_t ev = encf(V); \
                if (__builtin_expect((ID) < RMAX, 1)) atomicMax(&tab[(ID)*TP + c], ev); \
                else atomicMax(&agg[(size_t)ds_s[R]*HID + c], ev); }while(0)
            if (b01) FLUSH(rid[0], rb+0, v0); else v1 = fmaxf(v1, v0);
            if (b12) FLUSH(rid[1], rb+1, v1); else v2 = fmaxf(v2, v1);
            if (b23) FLUSH(rid[2], rb+2, v2); else v3 = fmaxf(v3, v2);
            FLUSH(rid[3], rb+3, v3);
            #undef FLUSH
        }
    }
    __syncthreads();                            // barrier2: table + run_dst complete

    {   // flush: boundary runs -> atomicMax; interior runs sole-writer -> plain store
        const int c = tid & 127;
        const int ntab = nruns < RMAX ? nruns : RMAX;
        for (int r = tid >> 7; r < ntab; r += 2){
            uint32_t v = tab[r*TP + c];
            uint32_t* dst = &agg[(size_t)run_dst_s[r]*HID + c];
            if (r == 0 || r == nruns-1 || nruns > RMAX) atomicMax(dst, v);
            else *dst = v;
        }
    }
}

// -------- fused layer-0 global nn + layer-1 A: out0 = relu((agg)@G1 + c1')@G2 + c2 ;
//          A1 = out0@W1a1 + B1 + b1_1 ; re-inits agg rows for layer 1 --------
// R5: weights from global (no Ws), Bh1 residual loaded direct from global in the
// epilogue -> 5 barriers (was 7), LDS 36.4 KB, (256,3).
__launch_bounds__(256, 3)
__global__ void k_gnn_ab(uint32_t* __restrict__ agg,
                         const _Float16* __restrict__ g1T, const _Float16* __restrict__ g2T,
                         const float* __restrict__ c1p, const float* __restrict__ gb2,
                         const _Float16* __restrict__ w1aT1, const _Float16* __restrict__ Bh1,
                         const float* __restrict__ lb1_1,
                         _Float16* __restrict__ Ah){
    __shared__ _Float16 Ts[128*LP];
    __shared__ float c1s[128];
    __shared__ float c2s[128];
    __shared__ float b1s[128];
    const int tid = threadIdx.x;
    const int node0 = blockIdx.x * 128;
    if (tid < 128){ c1s[tid] = c1p[tid]; c2s[tid] = gb2[tid]; b1s[tid] = lb1_1[tid]; }
    const int row = tid >> 1, half = tid & 1;

    {   // decode agg tile (+re-init to enc(-inf))
        uint4* ga = (uint4*)(agg + (size_t)(node0 + row)*HID + half*64);
        _Float16* lt = Ts + row*LP + half*64;
        const uint4 vneg = make_uint4(ENC_NEG, ENC_NEG, ENC_NEG, ENC_NEG);
        #pragma unroll
        for (int j = 0; j < 16; j++){
            uint4 u = ga[j];
            ga[j] = vneg;
            uint2 o; o.x = pkh(decf(u.x), decf(u.y)); o.y = pkh(decf(u.z), decf(u.w));
            *(uint2*)(lt + j*4) = o;
        }
    }
    __syncthreads();                                   // bar1: agg tile ready

    const int wv = tid >> 6, lane = tid & 63, lq = lane & 15, quad = lane >> 4;
    f32x4 acc[2][8];
    zero_acc(acc);
    gemm_tile_g(Ts, g1T, acc, wv, lq, quad);           // agg @ G1
    __syncthreads();                                   // bar2: Ts readers done

    #pragma unroll
    for (int rt = 0; rt < 2; rt++)
        #pragma unroll
        for (int ct = 0; ct < 8; ct++)
            #pragma unroll
            for (int rg = 0; rg < 4; rg++){
                int rr = wv*32 + rt*16 + quad*4 + rg;
                int c  = ct*16 + lq;
                Ts[rr*LP + c] = (_Float16)fmaxf(acc[rt][ct][rg] + c1s[c], 0.f);
            }
    __syncthreads();                                   // bar3: P tile ready

    zero_acc(acc);
    gemm_tile_g(Ts, g2T, acc, wv, lq, quad);           // P @ G2
    __syncthreads();                                   // bar4: Ts readers done

    #pragma unroll
    for (int rt = 0; rt < 2; rt++)                     // out0 -> Ts (fp16)
        #pragma unroll
        for (int ct = 0; ct < 8; ct++)
            #pragma unroll
            for (int rg = 0; rg < 4; rg++){
                int rr = wv*32 + rt*16 + quad*4 + rg;
                int c  = ct*16 + lq;
                Ts[rr*LP + c] = (_Float16)(acc[rt][ct][rg] + c2s[c]);
            }
    __syncthreads();                                   // bar5: out0 tile ready

    zero_acc(acc);
    gemm_tile_g(Ts, w1aT1, acc, wv, lq, quad);         // out0 @ W1a1

    #pragma unroll
    for (int rt = 0; rt < 2; rt++)
        #pragma unroll
        for (int ct = 0; ct < 8; ct++)
            #pragma unroll
            for (int rg = 0; rg < 4; rg++){
                int rr = wv*32 + rt*16 + quad*4 + rg;
                int c  = ct*16 + lq;
                size_t gi = (size_t)(node0 + rr)*HID + c;
                float v = acc[rt][ct][rg] + (float)Bh1[gi] + b1s[c];
                Ah[gi] = (_Float16)v;
            }
}

// -------- final global nn: out = relu(agg@G1 + c1') @ G2 + c2 --------
// R5: weights from global (no Ws) -> LDS 35.8 KB, (256,4), 3 barriers.
__launch_bounds__(256, 4)
__global__ void k_gnn(const uint32_t* __restrict__ agg,
                      const _Float16* __restrict__ g1T, const _Float16* __restrict__ g2T,
                      const float* __restrict__ c1p, const float* __restrict__ gb2,
                      float* __restrict__ outf){
    __shared__ _Float16 Ts[128*LP];
    __shared__ float c1s[128];
    __shared__ float c2s[128];
    const int tid = threadIdx.x;
    const int node0 = blockIdx.x * 128;
    if (tid < 128){ c1s[tid] = c1p[tid]; c2s[tid] = gb2[tid]; }
    const int row = tid >> 1, half = tid & 1;

    {   // decode agg tile
        const uint4* ga = (const uint4*)(agg + (size_t)(node0 + row)*HID + half*64);
        _Float16* lt = Ts + row*LP + half*64;
        #pragma unroll
        for (int j = 0; j < 16; j++){
            uint4 u = ga[j];
            uint2 o; o.x = pkh(decf(u.x), decf(u.y)); o.y = pkh(decf(u.z), decf(u.w));
            *(uint2*)(lt + j*4) = o;
        }
    }
    __syncthreads();                                   // bar1: agg tile ready

    const int wv = tid >> 6, lane = tid & 63, lq = lane & 15, quad = lane >> 4;
    f32x4 acc[2][8];
    zero_acc(acc);
    gemm_tile_g(Ts, g1T, acc, wv, lq, quad);
    __syncthreads();                                   // bar2: Ts readers done

    #pragma unroll
    for (int rt = 0; rt < 2; rt++)
        #pragma unroll
        for (int ct = 0; ct < 8; ct++)
            #pragma unroll
            for (int rg = 0; rg < 4; rg++){
                int rr = wv*32 + rt*16 + quad*4 + rg;
                int c  = ct*16 + lq;
                Ts[rr*LP + c] = (_Float16)fmaxf(acc[rt][ct][rg] + c1s[c], 0.f);
            }
    __syncthreads();                                   // bar3: P tile ready

    zero_acc(acc);
    gemm_tile_g(Ts, g2T, acc, wv, lq, quad);

    #pragma unroll
    for (int rt = 0; rt < 2; rt++)
        #pragma unroll
        for (int ct = 0; ct < 8; ct++)
            #pragma unroll
            for (int rg = 0; rg < 4; rg++){
                int r = node0 + wv*32 + rt*16 + quad*4 + rg;
                int c = ct*16 + lq;
                outf[(size_t)r*HID + c] = acc[rt][ct][rg] + c2s[c];
            }
}

extern "C" void kernel_launch(void* const* d_in, const int* in_sizes, int n_in,
                              void* d_out, int out_size, void* d_ws, size_t ws_size,
                              hipStream_t stream){
    const float* x   = (const float*)d_in[0];
    const float* pos = (const float*)d_in[1];
    const int*   ei  = (const int*)d_in[2];
    const float* W[16];
    for (int i = 0; i < 16; i++) W[i] = (const float*)d_in[3 + i];
    // per layer l: lw1=W[8l+0] lb1=+1 lw2=+2 lb2=+3 gw1=+4 gb1=+5 gw2=+6 gb2=+7

    uint8_t* p = (uint8_t*)d_ws;
    _Float16* wT[10];
    for (int i = 0; i < 10; i++) wT[i] = (_Float16*)(p + (size_t)i * 32768);
    size_t off = 10 * 32768;
    _Float16* Ah  = (_Float16*)(p + off); off += (size_t)NN * HID * 2;
    _Float16* Bh0 = (_Float16*)(p + off); off += (size_t)NN * HID * 2;
    _Float16* Bh1 = (_Float16*)(p + off); off += (size_t)NN * HID * 2;
    uint32_t* agg = (uint32_t*)(p + off); off += (size_t)NN * HID * 4;
    uint32_t* cnt = (uint32_t*)(p + off); off += (size_t)NN * 4;
    uint32_t* cur = (uint32_t*)(p + off); off += (size_t)NN * 4;
    uint32_t* bsum = (uint32_t*)(p + off); off += 256 * 4;
    uint32_t* bofs = (uint32_t*)(p + off); off += 256 * 4;
    float* c1p = (float*)(p + off); off += 256 * 4;
    uint2* sedge = (uint2*)(p + off); off += (size_t)E2 * 8;
    (void)ws_size; (void)in_sizes; (void)n_in; (void)out_size;

    // weight transpose slots per layer: W1a^T, W1b^T, W2^T, G1^T, G2^T
    WT wt;
    for (int l = 0; l < 2; l++){
        wt.s[5*l + 0] = W[8*l + 0];
        wt.s[5*l + 1] = W[8*l + 0] + 128*128;
        wt.s[5*l + 2] = W[8*l + 2];
        wt.s[5*l + 3] = W[8*l + 4];
        wt.s[5*l + 4] = W[8*l + 6];
        for (int j = 0; j < 5; j++) wt.d[5*l + j] = wT[5*l + j];
    }
    k_prep<<<898, 256, 0, stream>>>(wt, cnt, W[3], W[4], W[5], W[11], W[12], W[13], c1p);

    // dst-sorted edge list (shared by both layers)
    k_hist<<<NE/256, 256, 0, stream>>>(ei, cnt);
    k_scan1<<<256, 256, 0, stream>>>(cnt, bsum);
    k_scan2<<<1, 256, 0, stream>>>(bsum, bofs);
    k_scan3<<<256, 256, 0, stream>>>(cnt, bofs, cur);
    k_scatter<<<(E2 + 255)/256, 256, 0, stream>>>(ei, cur, sedge);

    k_ab3<<<NN/128, 256, 0, stream>>>(x, pos, wT[0], wT[1], wT[6], W[1],
                                      Ah, Bh0, Bh1, agg);
    k_edge<<<E2/128, 256, 0, stream>>>(sedge, Ah, Bh0, wT[2], agg);
    k_gnn_ab<<<NN/128, 256, 0, stream>>>(agg, wT[3], wT[4], c1p, W[7],
                                         wT[5], Bh1, W[9], Ah);
    k_edge<<<E2/128, 256, 0, stream>>>(sedge, Ah, Bh1, wT[7], agg);
    k_gnn<<<NN/128, 256, 0, stream>>>(agg, wT[8], wT[9], c1p + 128, W[15],
                                      (float*)d_out);
}

// Round 6
// 471.409 us; speedup vs baseline: 1.1256x; 1.1256x over previous
//
#include <hip/hip_runtime.h>
#include <hip/hip_bf16.h>
#include <stdint.h>

#define NN 65536
#define NE 1048576
#define E2 (NE + NN)      // edges + self loops = 1,114,112 = 8704*128
#define HID 128
#define LP 136            // padded LDS row pitch (fp16 elems) for node-kernel tiles
#define RMAX 13           // max runs in LDS run-table (overflow -> global atomics)
#define TP 129            // run-table stride in words
#define TABW 1680         // ceil(RMAX*TP/4)*4 words
#define ENC_NEG 0x007FFFFFu   // encf(-inf)

typedef _Float16 h8v __attribute__((ext_vector_type(8)));
typedef __fp16 fp16x2 __attribute__((ext_vector_type(2)));
typedef __attribute__((ext_vector_type(4))) float f32x4;

__device__ __forceinline__ uint32_t pkh(float a, float b){
    union { fp16x2 h; uint32_t u; } v;
    v.h = __builtin_amdgcn_cvt_pkrtz(a, b);
    return v.u;
}
// monotone float->uint encoding for unsigned atomicMax (branchless)
__device__ __forceinline__ uint32_t encf(float x){
    union { float f; uint32_t u; } v; v.f = x;
    return v.u ^ (uint32_t)(((int32_t)v.u >> 31) | 0x80000000);
}
__device__ __forceinline__ float decf(uint32_t u){
    union { uint32_t u; float f; } v;
    v.u = u ^ (uint32_t)(~((int32_t)u >> 31) | 0x80000000);
    return v.f;
}

// direct global->LDS DMA, 16B per lane (dest = wave-uniform base + lane*16)
__device__ __forceinline__ void gl_lds16(const _Float16* g, _Float16* l){
    __builtin_amdgcn_global_load_lds(
        (const __attribute__((address_space(1))) uint32_t*)g,
        (__attribute__((address_space(3))) uint32_t*)l, 16, 0, 0);
}

// ---- stage one 64-elem half-row into LDS (padded LP layout) ----
__device__ __forceinline__ void stage_copy(const _Float16* g, _Float16* l){
    const uint4* gs = (const uint4*)g; uint4* ls = (uint4*)l;
    #pragma unroll
    for (int j = 0; j < 8; j++) ls[j] = gs[j];
}
__device__ __forceinline__ void stage_cvt(const float* g, _Float16* l){
    const float4* gs = (const float4*)g; uint4* ls = (uint4*)l;
    #pragma unroll
    for (int j = 0; j < 8; j++){
        float4 f0 = gs[2*j], f1 = gs[2*j+1];
        uint4 o; o.x = pkh(f0.x, f0.y); o.y = pkh(f0.z, f0.w);
        o.z = pkh(f1.x, f1.y); o.w = pkh(f1.z, f1.w);
        ls[j] = o;
    }
}

// 128x128x128 fp16 GEMM from padded LDS tiles.
// R5 lesson: weights MUST be LDS-staged here -- direct-global B-fragments put
// L1/L2 latency on the MFMA critical path (-44 us total, R5 A/B).
__device__ __forceinline__ void gemm_tile(const _Float16* Ts, const _Float16* Ws,
                                          f32x4 (&acc)[2][8], int wv, int lq, int quad){
    #pragma unroll
    for (int k0 = 0; k0 < 128; k0 += 32){
        h8v af[2], bfr[8];
        #pragma unroll
        for (int rt = 0; rt < 2; rt++)
            af[rt] = *(const h8v*)(Ts + (wv*32 + rt*16 + lq)*LP + k0 + quad*8);
        #pragma unroll
        for (int ct = 0; ct < 8; ct++)
            bfr[ct] = *(const h8v*)(Ws + (ct*16 + lq)*LP + k0 + quad*8);
        #pragma unroll
        for (int rt = 0; rt < 2; rt++)
            #pragma unroll
            for (int ct = 0; ct < 8; ct++)
                acc[rt][ct] = __builtin_amdgcn_mfma_f32_16x16x32_f16(
                                  af[rt], bfr[ct], acc[rt][ct], 0, 0, 0);
    }
}

__device__ __forceinline__ void zero_acc(f32x4 (&acc)[2][8]){
    #pragma unroll
    for (int a = 0; a < 2; a++)
        #pragma unroll
        for (int b = 0; b < 8; b++)
            acc[a][b] = (f32x4){0.f, 0.f, 0.f, 0.f};
}

// ---------------- prep: weight transposes + cnt init + folded bias ----------------
struct WT { const float* s[10]; _Float16* d[10]; };
__global__ void k_prep(WT w, uint32_t* cnt,
                       const float* lb2_0, const float* gw1_0, const float* gb1_0,
                       const float* lb2_1, const float* gw1_1, const float* gb1_1,
                       float* c1p){
    int b = blockIdx.x;
    if (b < 640){
        int m = b >> 6;
        int t = (b & 63) * 256 + threadIdx.x;
        int n = t >> 7, k = t & 127;
        w.d[m][n*128 + k] = (_Float16)w.s[m][k*128 + n];
    } else if (b < 896){
        cnt[(b - 640)*256 + threadIdx.x] = 1u;        // self-loop pre-counted
    } else {
        // c1'[l][j] = gb1[j] + sum_k lb2[k]*gw1[k][j]   (folds b2 out of k_edge)
        int l = b - 896;
        int j = threadIdx.x;
        if (j < 128){
            const float* lb2 = l ? lb2_1 : lb2_0;
            const float* gw1 = l ? gw1_1 : gw1_0;
            float s = (l ? gb1_1 : gb1_0)[j];
            for (int k = 0; k < 128; k++) s += lb2[k] * gw1[k*128 + j];
            c1p[l*128 + j] = s;
        }
    }
}

// ---------------- fused hist + ab3 ----------------
// blocks 0..511: k_ab3 (R4-exact body); blocks 512..4607: edge histogram.
// Independent work (hist: ei->cnt; ab3: x,pos,W->Ah/Bh/agg), both dep only on
// k_prep -> legal fusion; hist blocks backfill CUs during ab3 drain/tail.
__launch_bounds__(256, 2)
__global__ void k_histab3(const int* __restrict__ ei, uint32_t* __restrict__ cnt,
                          const float* __restrict__ x, const float* __restrict__ pos,
                          const _Float16* __restrict__ w1aT0, const _Float16* __restrict__ w1bT0,
                          const _Float16* __restrict__ w1bT1, const float* __restrict__ lb1_0,
                          _Float16* __restrict__ Ah, _Float16* __restrict__ Bh0,
                          _Float16* __restrict__ Bh1, uint32_t* __restrict__ agg){
    __shared__ _Float16 Ts[128*LP];
    __shared__ _Float16 Ws[128*LP];
    __shared__ float b1s[128];
    const int tid = threadIdx.x;

    if (blockIdx.x >= 512){                            // ---- histogram part ----
        int e = (blockIdx.x - 512) * 256 + tid;
        atomicAdd(&cnt[ei[NE + e]], 1u);
        return;
    }

    // ---- ab3 part: B0 = pos@W1b0 ; B1 = pos@W1b1 ; A0 = x@W1a0 + B0 + b1_0 ----
    const int node0 = blockIdx.x * 128;
    if (tid < 128) b1s[tid] = lb1_0[tid];

    {   // init agg for this node range
        uint4* ap = (uint4*)(agg + (size_t)node0 * HID);
        uint4 v = make_uint4(ENC_NEG, ENC_NEG, ENC_NEG, ENC_NEG);
        #pragma unroll
        for (int i = 0; i < 16; i++) ap[tid + i*256] = v;
    }

    const int row = tid >> 1, half = tid & 1;
    _Float16* lT = Ts + row*LP + half*64;
    _Float16* lW = Ws + row*LP + half*64;

    stage_cvt(pos + (size_t)(node0 + row)*HID + half*64, lT);
    stage_copy(w1bT0 + row*HID + half*64, lW);
    __syncthreads();

    const int wv = tid >> 6, lane = tid & 63, lq = lane & 15, quad = lane >> 4;
    f32x4 acc0[2][8], acc1[2][8];
    zero_acc(acc0);
    gemm_tile(Ts, Ws, acc0, wv, lq, quad);     // acc0 = pos @ W1b0
    __syncthreads();

    #pragma unroll
    for (int rt = 0; rt < 2; rt++)
        #pragma unroll
        for (int ct = 0; ct < 8; ct++)
            #pragma unroll
            for (int rg = 0; rg < 4; rg++){
                int r = node0 + wv*32 + rt*16 + quad*4 + rg;
                int c = ct*16 + lq;
                Bh0[(size_t)r*HID + c] = (_Float16)acc0[rt][ct][rg];
            }
    stage_copy(w1bT1 + row*HID + half*64, lW);  // Ts (pos) kept
    __syncthreads();

    zero_acc(acc1);
    gemm_tile(Ts, Ws, acc1, wv, lq, quad);     // acc1 = pos @ W1b1
    __syncthreads();

    #pragma unroll
    for (int rt = 0; rt < 2; rt++)
        #pragma unroll
        for (int ct = 0; ct < 8; ct++)
            #pragma unroll
            for (int rg = 0; rg < 4; rg++){
                int r = node0 + wv*32 + rt*16 + quad*4 + rg;
                int c = ct*16 + lq;
                Bh1[(size_t)r*HID + c] = (_Float16)acc1[rt][ct][rg];
            }
    stage_cvt(x + (size_t)(node0 + row)*HID + half*64, lT);
    stage_copy(w1aT0 + row*HID + half*64, lW);
    __syncthreads();

    gemm_tile(Ts, Ws, acc0, wv, lq, quad);     // acc0 += x @ W1a0

    #pragma unroll
    for (int rt = 0; rt < 2; rt++)
        #pragma unroll
        for (int ct = 0; ct < 8; ct++)
            #pragma unroll
            for (int rg = 0; rg < 4; rg++){
                int r = node0 + wv*32 + rt*16 + quad*4 + rg;
                int c = ct*16 + lq;
                Ah[(size_t)r*HID + c] = (_Float16)(acc0[rt][ct][rg] + b1s[c]);
            }
}

__global__ void k_scan1(const uint32_t* __restrict__ cnt, uint32_t* __restrict__ bsum){
    __shared__ uint32_t ps[256];
    int t = threadIdx.x;
    ps[t] = cnt[blockIdx.x*256 + t]; __syncthreads();
    for (int off = 128; off > 0; off >>= 1){
        if (t < off) ps[t] += ps[t + off];
        __syncthreads();
    }
    if (t == 0) bsum[blockIdx.x] = ps[0];
}
// fused scan2+scan3: each block re-derives its bsum-prefix offset in LDS
// (256 extra loads/block -- trivial) -> one less launch + dependency bubble.
__global__ void k_scan23(const uint32_t* __restrict__ cnt, const uint32_t* __restrict__ bsum,
                         uint32_t* __restrict__ cur){
    __shared__ uint32_t ps[256];
    __shared__ uint32_t bs[256];
    int t = threadIdx.x, b = blockIdx.x, i = b*256 + t;
    uint32_t bb = bsum[b];
    bs[t] = bsum[t];
    uint32_t v = cnt[i];
    ps[t] = v; __syncthreads();
    for (int off = 1; off < 256; off <<= 1){
        uint32_t u = (t >= off) ? ps[t - off] : 0u;
        uint32_t w = (t >= off) ? bs[t - off] : 0u;
        __syncthreads();
        ps[t] += u; bs[t] += w;
        __syncthreads();
    }
    cur[i] = (bs[b] - bb) + ps[t] - v;
}
__global__ void k_scatter(const int* __restrict__ ei, uint32_t* cur,
                          uint2* __restrict__ sedge){
    int e = blockIdx.x * 256 + threadIdx.x;
    if (e >= E2) return;
    uint32_t s, d;
    if (e < NE){ s = (uint32_t)ei[e]; d = (uint32_t)ei[NE + e]; }
    else { s = d = (uint32_t)(e - NE); }
    uint32_t p = atomicAdd(&cur[d], 1u);
    sedge[p] = make_uint2(s, d);
}

// -------- edge kernel: agg[dst] = max over edges of relu(A[src]-B[dst]) @ W2 --------
// R4 structure (proven): 2 barriers, DMA-staged W2, per-lane edge loads, own-region
// run-table; 4 blocks/CU (LDS 40448, 128 unified regs).
__launch_bounds__(256, 4)
__global__ void k_edge(const uint2* __restrict__ sedge,
                       const _Float16* __restrict__ Ah, const _Float16* __restrict__ Bh,
                       const _Float16* __restrict__ w2T,
                       uint32_t* __restrict__ agg){
    __shared__ _Float16 Ws[128*128];                 // 32768 B, swizzled W2
    __shared__ __align__(16) uint32_t tab[TABW];     // 6720 B run-table (own region)
    __shared__ int ds_s[128];
    __shared__ unsigned long long masks_s[2];
    __shared__ int run_dst_s[RMAX];
    const int tid = threadIdx.x;
    const int bid = blockIdx.x;
    const int lb  = (bid & 7) * (E2/128/8) + (bid >> 3);   // XCD swizzle
    const int e0 = lb * 128;
    const int wv = tid >> 6, lane = tid & 63, lq = lane & 15, quad = lane >> 4;
    const int r0 = wv*32 + lq, r1 = r0 + 16;

    // ---- edge loads first (oldest in vmem FIFO -> cheap counted wait) ----
    const uint2 ea = sedge[e0 + r0];
    const uint2 eb = sedge[e0 + r1];
    int d_cur = 0;
    if (tid < 128) d_cur = (int)sedge[e0 + tid].y;

    // ---- W2 global->LDS DMA: linear dest, inverse-swizzled source ----
    #pragma unroll
    for (int rnd = 0; rnd < 8; rnd++){
        int g = rnd*256 + wv*64 + lane;              // 16B chunk id 0..2047
        int r = g >> 4, kc = g & 15;
        gl_lds16(w2T + r*HID + ((kc ^ (r & 15)) << 3),
                 Ws + rnd*2048 + wv*512);
    }

    // gathers: issue ASAP; drain at barrier1 under DMA + LDS bookkeeping
    const _Float16* a0p = Ah + (size_t)ea.x*HID + quad*8;
    const _Float16* a1p = Ah + (size_t)eb.x*HID + quad*8;
    const _Float16* b0p = Bh + (size_t)ea.y*HID + quad*8;
    const _Float16* b1p = Bh + (size_t)eb.y*HID + quad*8;
    h8v A0[4], A1[4], B0[4], B1[4];
    #pragma unroll
    for (int i = 0; i < 4; i++){
        A0[i] = *(const h8v*)(a0p + 32*i);
        A1[i] = *(const h8v*)(a1p + 32*i);
        B0[i] = *(const h8v*)(b0p + 32*i);
        B1[i] = *(const h8v*)(b1p + 32*i);
    }

    // boundary flags: d_prev via in-wave shuffles (no extra global loads).
    // lanes with (r1==63) hold sedge[e0+63] in eb -> shfl lane 15 serves tid 64.
    bool flag = false;
    if (tid < 128){
        ds_s[tid] = d_cur;
        int d_up  = __shfl_up(d_cur, 1);
        int d_b63 = __shfl((int)eb.y, 15);
        if (tid & 63) flag = (d_cur != d_up);
        else          flag = (tid == 0) ? true : (d_cur != d_b63);
        unsigned long long m = __ballot(flag);
        if ((tid & 63) == 0) masks_s[tid >> 6] = m;
    }
    {   // init run-table (TABW/4 = 420 uint4)
        uint4* t4 = (uint4*)tab;
        const uint4 vneg = make_uint4(ENC_NEG, ENC_NEG, ENC_NEG, ENC_NEG);
        #pragma unroll
        for (int i = 0; i < 2; i++){
            int idx = tid + i*256;
            if (idx < TABW/4) t4[idx] = vneg;
        }
    }
    __syncthreads();                            // barrier1: Ws/ds_s/masks/tab ready

    const unsigned long long m0 = masks_s[0], m1 = masks_s[1];
    const int c0 = __popcll(m0);
    const int nruns = c0 + __popcll(m1);

    // boundary threads record their run's dst (read post-barrier2 only)
    if (flag){
        int r;
        if (tid < 64) r = __popcll(m0 & ((2ull << tid) - 1)) - 1;
        else          r = c0 + __popcll(m1 & ((2ull << (tid-64)) - 1)) - 1;
        if (r < RMAX) run_dst_s[r] = d_cur;
    }

    f32x4 acc[2][8];
    zero_acc(acc);

    const h8v zero8 = (h8v)(_Float16)0;
    #pragma unroll
    for (int i = 0; i < 4; i++){
        h8v a0 = __builtin_elementwise_max(A0[i] - B0[i], zero8);
        h8v a1 = __builtin_elementwise_max(A1[i] - B1[i], zero8);
        const int kcb = i*4;
        #pragma unroll
        for (int ct = 0; ct < 8; ct++){
            h8v b = *(const h8v*)(Ws + (ct*16 + lq)*128 + (((kcb + quad) ^ lq) << 3));
            acc[0][ct] = __builtin_amdgcn_mfma_f32_16x16x32_f16(a0, b, acc[0][ct], 0, 0, 0);
            acc[1][ct] = __builtin_amdgcn_mfma_f32_16x16x32_f16(a1, b, acc[1][ct], 0, 0, 0);
        }
    }

    // flush acc -> run-table (tab does not alias Ws: no barrier needed)
    #pragma unroll
    for (int rt = 0; rt < 2; rt++){
        const int rb = wv*32 + rt*16 + quad*4;
        int rid[4];
        #pragma unroll
        for (int i = 0; i < 4; i++){
            int r = rb + i;
            if (r < 64) rid[i] = __popcll(m0 & ((2ull << r) - 1)) - 1;
            else        rid[i] = c0 + __popcll(m1 & ((2ull << (r-64)) - 1)) - 1;
        }
        const bool b01 = rid[1] != rid[0];
        const bool b12 = rid[2] != rid[1];
        const bool b23 = rid[3] != rid[2];
        #pragma unroll
        for (int ct = 0; ct < 8; ct++){
            const int c = ct*16 + lq;
            float v0 = acc[rt][ct][0], v1 = acc[rt][ct][1];
            float v2 = acc[rt][ct][2], v3 = acc[rt][ct][3];
            #define FLUSH(ID, R, V) do{ uint32_t ev = encf(V); \
                if (__builtin_expect((ID) < RMAX, 1)) atomicMax(&tab[(ID)*TP + c], ev); \
                else atomicMax(&agg[(size_t)ds_s[R]*HID + c], ev); }while(0)
            if (b01) FLUSH(rid[0], rb+0, v0); else v1 = fmaxf(v1, v0);
            if (b12) FLUSH(rid[1], rb+1, v1); else v2 = fmaxf(v2, v1);
            if (b23) FLUSH(rid[2], rb+2, v2); else v3 = fmaxf(v3, v2);
            FLUSH(rid[3], rb+3, v3);
            #undef FLUSH
        }
    }
    __syncthreads();                            // barrier2: table + run_dst complete

    {   // flush: boundary runs -> atomicMax; interior runs sole-writer -> plain store
        const int c = tid & 127;
        const int ntab = nruns < RMAX ? nruns : RMAX;
        for (int r = tid >> 7; r < ntab; r += 2){
            uint32_t v = tab[r*TP + c];
            uint32_t* dst = &agg[(size_t)run_dst_s[r]*HID + c];
            if (r == 0 || r == nruns-1 || nruns > RMAX) atomicMax(dst, v);
            else *dst = v;
        }
    }
}

// -------- fused layer-0 global nn + layer-1 A: out0 = relu((agg)@G1 + c1')@G2 + c2 ;
//          A1 = out0@W1a1 + B1 + b1_1 ; re-inits agg rows for layer 1 --------
__launch_bounds__(256, 2)
__global__ void k_gnn_ab(uint32_t* __restrict__ agg,
                         const _Float16* __restrict__ g1T, const _Float16* __restrict__ g2T,
                         const float* __restrict__ c1p, const float* __restrict__ gb2,
                         const _Float16* __restrict__ w1aT1, const _Float16* __restrict__ Bh1,
                         const float* __restrict__ lb1_1,
                         _Float16* __restrict__ Ah){
    __shared__ _Float16 Ts[128*LP];
    __shared__ _Float16 Ws[128*LP];
    __shared__ float c1s[128];
    __shared__ float c2s[128];
    __shared__ float b1s[128];
    const int tid = threadIdx.x;
    const int node0 = blockIdx.x * 128;
    if (tid < 128){ c1s[tid] = c1p[tid]; c2s[tid] = gb2[tid]; b1s[tid] = lb1_1[tid]; }
    const int row = tid >> 1, half = tid & 1;
    _Float16* lW = Ws + row*LP + half*64;

    {   // decode agg tile (+re-init to enc(-inf)) and stage G1^T
        uint4* ga = (uint4*)(agg + (size_t)(node0 + row)*HID + half*64);
        _Float16* lt = Ts + row*LP + half*64;
        const uint4 vneg = make_uint4(ENC_NEG, ENC_NEG, ENC_NEG, ENC_NEG);
        #pragma unroll
        for (int j = 0; j < 16; j++){
            uint4 u = ga[j];
            ga[j] = vneg;
            uint2 o; o.x = pkh(decf(u.x), decf(u.y)); o.y = pkh(decf(u.z), decf(u.w));
            *(uint2*)(lt + j*4) = o;
        }
        stage_copy(g1T + row*HID + half*64, lW);
    }
    __syncthreads();

    const int wv = tid >> 6, lane = tid & 63, lq = lane & 15, quad = lane >> 4;
    f32x4 acc[2][8];
    zero_acc(acc);
    gemm_tile(Ts, Ws, acc, wv, lq, quad);       // agg @ G1
    __syncthreads();

    #pragma unroll
    for (int rt = 0; rt < 2; rt++)
        #pragma unroll
        for (int ct = 0; ct < 8; ct++)
            #pragma unroll
            for (int rg = 0; rg < 4; rg++){
                int rr = wv*32 + rt*16 + quad*4 + rg;
                int c  = ct*16 + lq;
                Ts[rr*LP + c] = (_Float16)fmaxf(acc[rt][ct][rg] + c1s[c], 0.f);
            }
    stage_copy(g2T + row*HID + half*64, lW);
    __syncthreads();

    zero_acc(acc);
    gemm_tile(Ts, Ws, acc, wv, lq, quad);       // P @ G2
    __syncthreads();

    #pragma unroll
    for (int rt = 0; rt < 2; rt++)              // out0 -> Ts (fp16), stage W1a1^T
        #pragma unroll
        for (int ct = 0; ct < 8; ct++)
            #pragma unroll
            for (int rg = 0; rg < 4; rg++){
                int rr = wv*32 + rt*16 + quad*4 + rg;
                int c  = ct*16 + lq;
                Ts[rr*LP + c] = (_Float16)(acc[rt][ct][rg] + c2s[c]);
            }
    stage_copy(w1aT1 + row*HID + half*64, lW);
    __syncthreads();

    zero_acc(acc);
    gemm_tile(Ts, Ws, acc, wv, lq, quad);       // out0 @ W1a1
    __syncthreads();

    stage_copy(Bh1 + (size_t)(node0 + row)*HID + half*64, Ts + row*LP + half*64);
    __syncthreads();

    #pragma unroll
    for (int rt = 0; rt < 2; rt++)
        #pragma unroll
        for (int ct = 0; ct < 8; ct++)
            #pragma unroll
            for (int rg = 0; rg < 4; rg++){
                int rr = wv*32 + rt*16 + quad*4 + rg;
                int c  = ct*16 + lq;
                float v = acc[rt][ct][rg] + (float)Ts[rr*LP + c] + b1s[c];
                Ah[(size_t)(node0 + rr)*HID + c] = (_Float16)v;
            }
}

// -------- final global nn: out = relu(agg@G1 + c1') @ G2 + c2 --------
__launch_bounds__(256, 2)
__global__ void k_gnn(const uint32_t* __restrict__ agg,
                      const _Float16* __restrict__ g1T, const _Float16* __restrict__ g2T,
                      const float* __restrict__ c1p, const float* __restrict__ gb2,
                      float* __restrict__ outf){
    __shared__ _Float16 Ts[128*LP];
    __shared__ _Float16 Ws[128*LP];
    __shared__ float c1s[128];
    __shared__ float c2s[128];
    const int tid = threadIdx.x;
    const int node0 = blockIdx.x * 128;
    if (tid < 128){ c1s[tid] = c1p[tid]; c2s[tid] = gb2[tid]; }
    const int row = tid >> 1, half = tid & 1;
    _Float16* lW = Ws + row*LP + half*64;

    {   // decode agg tile + stage G1^T
        const uint4* ga = (const uint4*)(agg + (size_t)(node0 + row)*HID + half*64);
        _Float16* lt = Ts + row*LP + half*64;
        #pragma unroll
        for (int j = 0; j < 16; j++){
            uint4 u = ga[j];
            uint2 o; o.x = pkh(decf(u.x), decf(u.y)); o.y = pkh(decf(u.z), decf(u.w));
            *(uint2*)(lt + j*4) = o;
        }
        stage_copy(g1T + row*HID + half*64, lW);
    }
    __syncthreads();

    const int wv = tid >> 6, lane = tid & 63, lq = lane & 15, quad = lane >> 4;
    f32x4 acc[2][8];
    zero_acc(acc);
    gemm_tile(Ts, Ws, acc, wv, lq, quad);
    __syncthreads();

    #pragma unroll
    for (int rt = 0; rt < 2; rt++)
        #pragma unroll
        for (int ct = 0; ct < 8; ct++)
            #pragma unroll
            for (int rg = 0; rg < 4; rg++){
                int rr = wv*32 + rt*16 + quad*4 + rg;
                int c  = ct*16 + lq;
                Ts[rr*LP + c] = (_Float16)fmaxf(acc[rt][ct][rg] + c1s[c], 0.f);
            }
    stage_copy(g2T + row*HID + half*64, lW);
    __syncthreads();

    zero_acc(acc);
    gemm_tile(Ts, Ws, acc, wv, lq, quad);

    #pragma unroll
    for (int rt = 0; rt < 2; rt++)
        #pragma unroll
        for (int ct = 0; ct < 8; ct++)
            #pragma unroll
            for (int rg = 0; rg < 4; rg++){
                int r = node0 + wv*32 + rt*16 + quad*4 + rg;
                int c = ct*16 + lq;
                outf[(size_t)r*HID + c] = acc[rt][ct][rg] + c2s[c];
            }
}

extern "C" void kernel_launch(void* const* d_in, const int* in_sizes, int n_in,
                              void* d_out, int out_size, void* d_ws, size_t ws_size,
                              hipStream_t stream){
    const float* x   = (const float*)d_in[0];
    const float* pos = (const float*)d_in[1];
    const int*   ei  = (const int*)d_in[2];
    const float* W[16];
    for (int i = 0; i < 16; i++) W[i] = (const float*)d_in[3 + i];
    // per layer l: lw1=W[8l+0] lb1=+1 lw2=+2 lb2=+3 gw1=+4 gb1=+5 gw2=+6 gb2=+7

    uint8_t* p = (uint8_t*)d_ws;
    _Float16* wT[10];
    for (int i = 0; i < 10; i++) wT[i] = (_Float16*)(p + (size_t)i * 32768);
    size_t off = 10 * 32768;
    _Float16* Ah  = (_Float16*)(p + off); off += (size_t)NN * HID * 2;
    _Float16* Bh0 = (_Float16*)(p + off); off += (size_t)NN * HID * 2;
    _Float16* Bh1 = (_Float16*)(p + off); off += (size_t)NN * HID * 2;
    uint32_t* agg = (uint32_t*)(p + off); off += (size_t)NN * HID * 4;
    uint32_t* cnt = (uint32_t*)(p + off); off += (size_t)NN * 4;
    uint32_t* cur = (uint32_t*)(p + off); off += (size_t)NN * 4;
    uint32_t* bsum = (uint32_t*)(p + off); off += 256 * 4;
    uint32_t* bofs = (uint32_t*)(p + off); off += 256 * 4;
    float* c1p = (float*)(p + off); off += 256 * 4;
    uint2* sedge = (uint2*)(p + off); off += (size_t)E2 * 8;
    (void)ws_size; (void)in_sizes; (void)n_in; (void)out_size; (void)bofs;

    // weight transpose slots per layer: W1a^T, W1b^T, W2^T, G1^T, G2^T
    WT wt;
    for (int l = 0; l < 2; l++){
        wt.s[5*l + 0] = W[8*l + 0];
        wt.s[5*l + 1] = W[8*l + 0] + 128*128;
        wt.s[5*l + 2] = W[8*l + 2];
        wt.s[5*l + 3] = W[8*l + 4];
        wt.s[5*l + 4] = W[8*l + 6];
        for (int j = 0; j < 5; j++) wt.d[5*l + j] = wT[5*l + j];
    }
    k_prep<<<898, 256, 0, stream>>>(wt, cnt, W[3], W[4], W[5], W[11], W[12], W[13], c1p);

    // fused: layer-0 A/B GEMMs (blocks 0-511) + edge histogram (blocks 512-4607)
    k_histab3<<<512 + NE/256, 256, 0, stream>>>(ei, cnt, x, pos, wT[0], wT[1], wT[6],
                                                W[1], Ah, Bh0, Bh1, agg);
    k_scan1<<<256, 256, 0, stream>>>(cnt, bsum);
    k_scan23<<<256, 256, 0, stream>>>(cnt, bsum, cur);
    k_scatter<<<(E2 + 255)/256, 256, 0, stream>>>(ei, cur, sedge);

    k_edge<<<E2/128, 256, 0, stream>>>(sedge, Ah, Bh0, wT[2], agg);
    k_gnn_ab<<<NN/128, 256, 0, stream>>>(agg, wT[3], wT[4], c1p, W[7],
                                         wT[5], Bh1, W[9], Ah);
    k_edge<<<E2/128, 256, 0, stream>>>(sedge, Ah, Bh1, wT[7], agg);
    k_gnn<<<NN/128, 256, 0, stream>>>(agg, wT[8], wT[9], c1p + 128, W[15],
                                      (float*)d_out);
}

// Round 7
// 452.372 us; speedup vs baseline: 1.1729x; 1.0421x over previous
//
#include <hip/hip_runtime.h>
#include <hip/hip_bf16.h>
#include <stdint.h>

#define NN 65536
#define NE 1048576
#define E2 (NE + NN)      // edges + self loops = 1,114,112 = 8704*128
#define HID 128
#define LP 136            // padded LDS row pitch (fp16 elems) for node-kernel A tiles
#define RMAX 13           // max runs in LDS run-table (overflow -> global atomics)
#define TP 129            // run-table stride in words
#define TABW 1680         // ceil(RMAX*TP/4)*4 words
#define ENC_NEG 0x007FFFFFu   // encf(-inf)

typedef _Float16 h8v __attribute__((ext_vector_type(8)));
typedef __fp16 fp16x2 __attribute__((ext_vector_type(2)));
typedef __attribute__((ext_vector_type(4))) float f32x4;

__device__ __forceinline__ uint32_t pkh(float a, float b){
    union { fp16x2 h; uint32_t u; } v;
    v.h = __builtin_amdgcn_cvt_pkrtz(a, b);
    return v.u;
}
// monotone float->uint encoding for unsigned atomicMax (branchless)
__device__ __forceinline__ uint32_t encf(float x){
    union { float f; uint32_t u; } v; v.f = x;
    return v.u ^ (uint32_t)(((int32_t)v.u >> 31) | 0x80000000);
}
__device__ __forceinline__ float decf(uint32_t u){
    union { uint32_t u; float f; } v;
    v.u = u ^ (uint32_t)(~((int32_t)u >> 31) | 0x80000000);
    return v.f;
}

// direct global->LDS DMA, 16B per lane (dest = wave-uniform base + lane*16)
__device__ __forceinline__ void gl_lds16(const _Float16* g, _Float16* l){
    __builtin_amdgcn_global_load_lds(
        (const __attribute__((address_space(1))) uint32_t*)g,
        (__attribute__((address_space(3))) uint32_t*)l, 16, 0, 0);
}

// stage a 128x128 fp16 weight into LDS via DMA: linear dest, inverse-XOR-swizzled
// per-lane global source (k_edge-proven). Read side uses the same XOR (involution).
__device__ __forceinline__ void dma_w(const _Float16* __restrict__ wT, _Float16* Ws,
                                      int wv, int lane){
    #pragma unroll
    for (int rnd = 0; rnd < 8; rnd++){
        int g = rnd*256 + wv*64 + lane;              // 16B chunk id 0..2047
        int r = g >> 4, kc = g & 15;
        gl_lds16(wT + r*HID + ((kc ^ (r & 15)) << 3),
                 Ws + rnd*2048 + wv*512);
    }
}

// 64x128x128 fp16 GEMM: A from padded LDS tile (64 rows), B from swizzled Ws.
// Each wave computes 16 output rows (wv*16..+15); acc[ct] covers col ct*16+lq,
// rows quad*4+rg. R5 lesson: weights must be LDS-resident, not direct-global.
__device__ __forceinline__ void gemm64(const _Float16* Ts, const _Float16* Ws,
                                       f32x4 (&acc)[8], int wv, int lq, int quad){
    #pragma unroll
    for (int k0 = 0; k0 < 128; k0 += 32){
        h8v af = *(const h8v*)(Ts + (wv*16 + lq)*LP + k0 + quad*8);
        const int kcb = k0 >> 3;
        #pragma unroll
        for (int ct = 0; ct < 8; ct++){
            h8v b = *(const h8v*)(Ws + (ct*16 + lq)*128 + (((kcb + quad) ^ lq) << 3));
            acc[ct] = __builtin_amdgcn_mfma_f32_16x16x32_f16(af, b, acc[ct], 0, 0, 0);
        }
    }
}

__device__ __forceinline__ void zero_acc8(f32x4 (&acc)[8]){
    #pragma unroll
    for (int b = 0; b < 8; b++) acc[b] = (f32x4){0.f, 0.f, 0.f, 0.f};
}

__device__ __forceinline__ void zero_acc(f32x4 (&acc)[2][8]){
    #pragma unroll
    for (int a = 0; a < 2; a++)
        #pragma unroll
        for (int b = 0; b < 8; b++)
            acc[a][b] = (f32x4){0.f, 0.f, 0.f, 0.f};
}

// ---------------- prep: weight transposes + cnt init + folded bias ----------------
struct WT { const float* s[10]; _Float16* d[10]; };
__global__ void k_prep(WT w, uint32_t* cnt,
                       const float* lb2_0, const float* gw1_0, const float* gb1_0,
                       const float* lb2_1, const float* gw1_1, const float* gb1_1,
                       float* c1p){
    int b = blockIdx.x;
    if (b < 640){
        int m = b >> 6;
        int t = (b & 63) * 256 + threadIdx.x;
        int n = t >> 7, k = t & 127;
        w.d[m][n*128 + k] = (_Float16)w.s[m][k*128 + n];
    } else if (b < 896){
        cnt[(b - 640)*256 + threadIdx.x] = 1u;        // self-loop pre-counted
    } else {
        // c1'[l][j] = gb1[j] + sum_k lb2[k]*gw1[k][j]   (folds b2 out of k_edge)
        int l = b - 896;
        int j = threadIdx.x;
        if (j < 128){
            const float* lb2 = l ? lb2_1 : lb2_0;
            const float* gw1 = l ? gw1_1 : gw1_0;
            float s = (l ? gb1_1 : gb1_0)[j];
            for (int k = 0; k < 128; k++) s += lb2[k] * gw1[k*128 + j];
            c1p[l*128 + j] = s;
        }
    }
}

// ---------------- fused hist + ab3 (64-row tiles) ----------------
// blocks 0..1023: ab3; blocks 1024..5119: edge histogram.
// B0 = pos@W1b0 ; B1 = pos@W1b1 ; A0 = x@W1a0 + B0 + b1_0 ; agg init.
// LDS: Ts 17.4K + Ws 32.8K ~ 51K -> 3 blocks/CU (was 2 at 69.6K).
__launch_bounds__(256, 3)
__global__ void k_histab3(const int* __restrict__ ei, uint32_t* __restrict__ cnt,
                          const float* __restrict__ x, const float* __restrict__ pos,
                          const _Float16* __restrict__ w1aT0, const _Float16* __restrict__ w1bT0,
                          const _Float16* __restrict__ w1bT1, const float* __restrict__ lb1_0,
                          _Float16* __restrict__ Ah, _Float16* __restrict__ Bh0,
                          _Float16* __restrict__ Bh1, uint32_t* __restrict__ agg){
    __shared__ _Float16 Ts[64*LP];
    __shared__ _Float16 Ws[128*128];
    __shared__ float b1s[128];
    const int tid = threadIdx.x;

    if (blockIdx.x >= 1024){                           // ---- histogram part ----
        int e = (blockIdx.x - 1024) * 256 + tid;
        atomicAdd(&cnt[ei[NE + e]], 1u);
        return;
    }

    const int node0 = blockIdx.x * 64;
    const int wv = tid >> 6, lane = tid & 63, lq = lane & 15, quad = lane >> 4;
    if (tid < 128) b1s[tid] = lb1_0[tid];

    {   // init agg for this node range (64 rows)
        uint4* ap = (uint4*)(agg + (size_t)node0 * HID);
        uint4 v = make_uint4(ENC_NEG, ENC_NEG, ENC_NEG, ENC_NEG);
        #pragma unroll
        for (int i = 0; i < 8; i++) ap[tid + i*256] = v;
    }
    // stage pos -> Ts (chunk-linear: fully coalesced reads)
    #pragma unroll
    for (int i = 0; i < 8; i++){
        int chunk = tid + i*256;
        int row = chunk >> 5, qc = chunk & 31;
        float4 f = *(const float4*)(pos + (size_t)(node0 + row)*HID + qc*4);
        uint2 o; o.x = pkh(f.x, f.y); o.y = pkh(f.z, f.w);
        *(uint2*)(Ts + row*LP + qc*4) = o;
    }
    dma_w(w1bT0, Ws, wv, lane);
    __syncthreads();                                   // bar1: Ts+Ws ready

    f32x4 acc0[8], acc1[8];
    zero_acc8(acc0);
    gemm64(Ts, Ws, acc0, wv, lq, quad);                // pos @ W1b0
    __syncthreads();                                   // bar2: Ws readers done
    dma_w(w1bT1, Ws, wv, lane);
    #pragma unroll
    for (int ct = 0; ct < 8; ct++)
        #pragma unroll
        for (int rg = 0; rg < 4; rg++)
            Bh0[(size_t)(node0 + wv*16 + quad*4 + rg)*HID + ct*16 + lq]
                = (_Float16)acc0[ct][rg];
    __syncthreads();                                   // bar3: Ws ready

    zero_acc8(acc1);
    gemm64(Ts, Ws, acc1, wv, lq, quad);                // pos @ W1b1
    __syncthreads();                                   // bar4: Ts+Ws readers done

    #pragma unroll
    for (int i = 0; i < 8; i++){                       // stage x -> Ts
        int chunk = tid + i*256;
        int row = chunk >> 5, qc = chunk & 31;
        float4 f = *(const float4*)(x + (size_t)(node0 + row)*HID + qc*4);
        uint2 o; o.x = pkh(f.x, f.y); o.y = pkh(f.z, f.w);
        *(uint2*)(Ts + row*LP + qc*4) = o;
    }
    dma_w(w1aT0, Ws, wv, lane);
    #pragma unroll
    for (int ct = 0; ct < 8; ct++)
        #pragma unroll
        for (int rg = 0; rg < 4; rg++)
            Bh1[(size_t)(node0 + wv*16 + quad*4 + rg)*HID + ct*16 + lq]
                = (_Float16)acc1[ct][rg];
    __syncthreads();                                   // bar5: Ts+Ws ready

    gemm64(Ts, Ws, acc0, wv, lq, quad);                // acc0 += x @ W1a0

    #pragma unroll
    for (int ct = 0; ct < 8; ct++)
        #pragma unroll
        for (int rg = 0; rg < 4; rg++){
            int c = ct*16 + lq;
            Ah[(size_t)(node0 + wv*16 + quad*4 + rg)*HID + c]
                = (_Float16)(acc0[ct][rg] + b1s[c]);
        }
}

__global__ void k_scan1(const uint32_t* __restrict__ cnt, uint32_t* __restrict__ bsum){
    __shared__ uint32_t ps[256];
    int t = threadIdx.x;
    ps[t] = cnt[blockIdx.x*256 + t]; __syncthreads();
    for (int off = 128; off > 0; off >>= 1){
        if (t < off) ps[t] += ps[t + off];
        __syncthreads();
    }
    if (t == 0) bsum[blockIdx.x] = ps[0];
}
// fused scan2+scan3: each block re-derives its bsum-prefix offset in LDS
__global__ void k_scan23(const uint32_t* __restrict__ cnt, const uint32_t* __restrict__ bsum,
                         uint32_t* __restrict__ cur){
    __shared__ uint32_t ps[256];
    __shared__ uint32_t bs[256];
    int t = threadIdx.x, b = blockIdx.x, i = b*256 + t;
    uint32_t bb = bsum[b];
    bs[t] = bsum[t];
    uint32_t v = cnt[i];
    ps[t] = v; __syncthreads();
    for (int off = 1; off < 256; off <<= 1){
        uint32_t u = (t >= off) ? ps[t - off] : 0u;
        uint32_t w = (t >= off) ? bs[t - off] : 0u;
        __syncthreads();
        ps[t] += u; bs[t] += w;
        __syncthreads();
    }
    cur[i] = (bs[b] - bb) + ps[t] - v;
}
__global__ void k_scatter(const int* __restrict__ ei, uint32_t* cur,
                          uint2* __restrict__ sedge){
    int e = blockIdx.x * 256 + threadIdx.x;
    if (e >= E2) return;
    uint32_t s, d;
    if (e < NE){ s = (uint32_t)ei[e]; d = (uint32_t)ei[NE + e]; }
    else { s = d = (uint32_t)(e - NE); }
    uint32_t p = atomicAdd(&cur[d], 1u);
    sedge[p] = make_uint2(s, d);
}

// -------- edge kernel: agg[dst] = max over edges of relu(A[src]-B[dst]) @ W2 --------
// R4 structure (proven): 2 barriers, DMA-staged W2, per-lane edge loads, own-region
// run-table; 4 blocks/CU (LDS 40448, 128 unified regs).
__launch_bounds__(256, 4)
__global__ void k_edge(const uint2* __restrict__ sedge,
                       const _Float16* __restrict__ Ah, const _Float16* __restrict__ Bh,
                       const _Float16* __restrict__ w2T,
                       uint32_t* __restrict__ agg){
    __shared__ _Float16 Ws[128*128];                 // 32768 B, swizzled W2
    __shared__ __align__(16) uint32_t tab[TABW];     // 6720 B run-table (own region)
    __shared__ int ds_s[128];
    __shared__ unsigned long long masks_s[2];
    __shared__ int run_dst_s[RMAX];
    const int tid = threadIdx.x;
    const int bid = blockIdx.x;
    const int lb  = (bid & 7) * (E2/128/8) + (bid >> 3);   // XCD swizzle
    const int e0 = lb * 128;
    const int wv = tid >> 6, lane = tid & 63, lq = lane & 15, quad = lane >> 4;
    const int r0 = wv*32 + lq, r1 = r0 + 16;

    // ---- edge loads first (oldest in vmem FIFO -> cheap counted wait) ----
    const uint2 ea = sedge[e0 + r0];
    const uint2 eb = sedge[e0 + r1];
    int d_cur = 0;
    if (tid < 128) d_cur = (int)sedge[e0 + tid].y;

    // ---- W2 global->LDS DMA: linear dest, inverse-swizzled source ----
    dma_w(w2T, Ws, wv, lane);

    // gathers: issue ASAP; drain at barrier1 under DMA + LDS bookkeeping
    const _Float16* a0p = Ah + (size_t)ea.x*HID + quad*8;
    const _Float16* a1p = Ah + (size_t)eb.x*HID + quad*8;
    const _Float16* b0p = Bh + (size_t)ea.y*HID + quad*8;
    const _Float16* b1p = Bh + (size_t)eb.y*HID + quad*8;
    h8v A0[4], A1[4], B0[4], B1[4];
    #pragma unroll
    for (int i = 0; i < 4; i++){
        A0[i] = *(const h8v*)(a0p + 32*i);
        A1[i] = *(const h8v*)(a1p + 32*i);
        B0[i] = *(const h8v*)(b0p + 32*i);
        B1[i] = *(const h8v*)(b1p + 32*i);
    }

    // boundary flags: d_prev via in-wave shuffles (no extra global loads).
    // lanes with (r1==63) hold sedge[e0+63] in eb -> shfl lane 15 serves tid 64.
    bool flag = false;
    if (tid < 128){
        ds_s[tid] = d_cur;
        int d_up  = __shfl_up(d_cur, 1);
        int d_b63 = __shfl((int)eb.y, 15);
        if (tid & 63) flag = (d_cur != d_up);
        else          flag = (tid == 0) ? true : (d_cur != d_b63);
        unsigned long long m = __ballot(flag);
        if ((tid & 63) == 0) masks_s[tid >> 6] = m;
    }
    {   // init run-table (TABW/4 = 420 uint4)
        uint4* t4 = (uint4*)tab;
        const uint4 vneg = make_uint4(ENC_NEG, ENC_NEG, ENC_NEG, ENC_NEG);
        #pragma unroll
        for (int i = 0; i < 2; i++){
            int idx = tid + i*256;
            if (idx < TABW/4) t4[idx] = vneg;
        }
    }
    __syncthreads();                            // barrier1: Ws/ds_s/masks/tab ready

    const unsigned long long m0 = masks_s[0], m1 = masks_s[1];
    const int c0 = __popcll(m0);
    const int nruns = c0 + __popcll(m1);

    // boundary threads record their run's dst (read post-barrier2 only)
    if (flag){
        int r;
        if (tid < 64) r = __popcll(m0 & ((2ull << tid) - 1)) - 1;
        else          r = c0 + __popcll(m1 & ((2ull << (tid-64)) - 1)) - 1;
        if (r < RMAX) run_dst_s[r] = d_cur;
    }

    f32x4 acc[2][8];
    zero_acc(acc);

    const h8v zero8 = (h8v)(_Float16)0;
    #pragma unroll
    for (int i = 0; i < 4; i++){
        h8v a0 = __builtin_elementwise_max(A0[i] - B0[i], zero8);
        h8v a1 = __builtin_elementwise_max(A1[i] - B1[i], zero8);
        const int kcb = i*4;
        #pragma unroll
        for (int ct = 0; ct < 8; ct++){
            h8v b = *(const h8v*)(Ws + (ct*16 + lq)*128 + (((kcb + quad) ^ lq) << 3));
            acc[0][ct] = __builtin_amdgcn_mfma_f32_16x16x32_f16(a0, b, acc[0][ct], 0, 0, 0);
            acc[1][ct] = __builtin_amdgcn_mfma_f32_16x16x32_f16(a1, b, acc[1][ct], 0, 0, 0);
        }
    }

    // flush acc -> run-table (tab does not alias Ws: no barrier needed)
    #pragma unroll
    for (int rt = 0; rt < 2; rt++){
        const int rb = wv*32 + rt*16 + quad*4;
        int rid[4];
        #pragma unroll
        for (int i = 0; i < 4; i++){
            int r = rb + i;
            if (r < 64) rid[i] = __popcll(m0 & ((2ull << r) - 1)) - 1;
            else        rid[i] = c0 + __popcll(m1 & ((2ull << (r-64)) - 1)) - 1;
        }
        const bool b01 = rid[1] != rid[0];
        const bool b12 = rid[2] != rid[1];
        const bool b23 = rid[3] != rid[2];
        #pragma unroll
        for (int ct = 0; ct < 8; ct++){
            const int c = ct*16 + lq;
            float v0 = acc[rt][ct][0], v1 = acc[rt][ct][1];
            float v2 = acc[rt][ct][2], v3 = acc[rt][ct][3];
            #define FLUSH(ID, R, V) do{ uint32_t ev = encf(V); \
                if (__builtin_expect((ID) < RMAX, 1)) atomicMax(&tab[(ID)*TP + c], ev); \
                else atomicMax(&agg[(size_t)ds_s[R]*HID + c], ev); }while(0)
            if (b01) FLUSH(rid[0], rb+0, v0); else v1 = fmaxf(v1, v0);
            if (b12) FLUSH(rid[1], rb+1, v1); else v2 = fmaxf(v2, v1);
            if (b23) FLUSH(rid[2], rb+2, v2); else v3 = fmaxf(v3, v2);
            FLUSH(rid[3], rb+3, v3);
            #undef FLUSH
        }
    }
    __syncthreads();                            // barrier2: table + run_dst complete

    {   // flush: boundary runs -> atomicMax; interior runs sole-writer -> plain store
        const int c = tid & 127;
        const int ntab = nruns < RMAX ? nruns : RMAX;
        for (int r = tid >> 7; r < ntab; r += 2){
            uint32_t v = tab[r*TP + c];
            uint32_t* dst = &agg[(size_t)run_dst_s[r]*HID + c];
            if (r == 0 || r == nruns-1 || nruns > RMAX) atomicMax(dst, v);
            else *dst = v;
        }
    }
}

// -------- fused layer-0 global nn + layer-1 A (64-row tiles): out0 = relu(agg@G1
//          + c1')@G2 + c2 ; A1 = out0@W1a1 + B1 + b1_1 ; re-inits agg rows --------
// LDS ~51K -> 3 blocks/CU; Bh1 residual prefetched into regs before GEMM3.
__launch_bounds__(256, 3)
__global__ void k_gnn_ab(uint32_t* __restrict__ agg,
                         const _Float16* __restrict__ g1T, const _Float16* __restrict__ g2T,
                         const float* __restrict__ c1p, const float* __restrict__ gb2,
                         const _Float16* __restrict__ w1aT1, const _Float16* __restrict__ Bh1,
                         const float* __restrict__ lb1_1,
                         _Float16* __restrict__ Ah){
    __shared__ _Float16 Ts[64*LP];
    __shared__ _Float16 Ws[128*128];
    __shared__ float c1s[128];
    __shared__ float c2s[128];
    __shared__ float b1s[128];
    const int tid = threadIdx.x;
    const int node0 = blockIdx.x * 64;
    const int wv = tid >> 6, lane = tid & 63, lq = lane & 15, quad = lane >> 4;
    if (tid < 128){ c1s[tid] = c1p[tid]; c2s[tid] = gb2[tid]; b1s[tid] = lb1_1[tid]; }

    {   // decode agg -> Ts (+re-init), chunk-linear coalesced
        const uint4 vneg = make_uint4(ENC_NEG, ENC_NEG, ENC_NEG, ENC_NEG);
        #pragma unroll
        for (int i = 0; i < 8; i++){
            int chunk = tid + i*256;
            int row = chunk >> 5, qc = chunk & 31;
            uint4* ga = (uint4*)(agg + (size_t)(node0 + row)*HID + qc*4);
            uint4 u = *ga; *ga = vneg;
            uint2 o; o.x = pkh(decf(u.x), decf(u.y)); o.y = pkh(decf(u.z), decf(u.w));
            *(uint2*)(Ts + row*LP + qc*4) = o;
        }
    }
    dma_w(g1T, Ws, wv, lane);
    __syncthreads();                                   // bar1

    f32x4 acc[8];
    zero_acc8(acc);
    gemm64(Ts, Ws, acc, wv, lq, quad);                 // agg @ G1
    __syncthreads();                                   // bar2: Ts+Ws readers done
    dma_w(g2T, Ws, wv, lane);
    #pragma unroll
    for (int ct = 0; ct < 8; ct++)
        #pragma unroll
        for (int rg = 0; rg < 4; rg++){
            int c = ct*16 + lq;
            Ts[(wv*16 + quad*4 + rg)*LP + c] = (_Float16)fmaxf(acc[ct][rg] + c1s[c], 0.f);
        }
    __syncthreads();                                   // bar3

    zero_acc8(acc);
    gemm64(Ts, Ws, acc, wv, lq, quad);                 // P @ G2
    __syncthreads();                                   // bar4
    dma_w(w1aT1, Ws, wv, lane);
    #pragma unroll
    for (int ct = 0; ct < 8; ct++)
        #pragma unroll
        for (int rg = 0; rg < 4; rg++){
            int c = ct*16 + lq;
            Ts[(wv*16 + quad*4 + rg)*LP + c] = (_Float16)(acc[ct][rg] + c2s[c]);
        }
    __syncthreads();                                   // bar5

    // prefetch Bh1 residual into regs (latency hidden under GEMM3)
    _Float16 bres[8][4];
    #pragma unroll
    for (int ct = 0; ct < 8; ct++)
        #pragma unroll
        for (int rg = 0; rg < 4; rg++)
            bres[ct][rg] = Bh1[(size_t)(node0 + wv*16 + quad*4 + rg)*HID + ct*16 + lq];

    zero_acc8(acc);
    gemm64(Ts, Ws, acc, wv, lq, quad);                 // out0 @ W1a1

    #pragma unroll
    for (int ct = 0; ct < 8; ct++)
        #pragma unroll
        for (int rg = 0; rg < 4; rg++){
            int c = ct*16 + lq;
            float v = acc[ct][rg] + (float)bres[ct][rg] + b1s[c];
            Ah[(size_t)(node0 + wv*16 + quad*4 + rg)*HID + c] = (_Float16)v;
        }
}

// -------- final global nn (64-row tiles): out = relu(agg@G1 + c1') @ G2 + c2 ----
__launch_bounds__(256, 3)
__global__ void k_gnn(const uint32_t* __restrict__ agg,
                      const _Float16* __restrict__ g1T, const _Float16* __restrict__ g2T,
                      const float* __restrict__ c1p, const float* __restrict__ gb2,
                      float* __restrict__ outf){
    __shared__ _Float16 Ts[64*LP];
    __shared__ _Float16 Ws[128*128];
    __shared__ float c1s[128];
    __shared__ float c2s[128];
    const int tid = threadIdx.x;
    const int node0 = blockIdx.x * 64;
    const int wv = tid >> 6, lane = tid & 63, lq = lane & 15, quad = lane >> 4;
    if (tid < 128){ c1s[tid] = c1p[tid]; c2s[tid] = gb2[tid]; }

    {   // decode agg -> Ts, chunk-linear coalesced
        #pragma unroll
        for (int i = 0; i < 8; i++){
            int chunk = tid + i*256;
            int row = chunk >> 5, qc = chunk & 31;
            const uint4* ga = (const uint4*)(agg + (size_t)(node0 + row)*HID + qc*4);
            uint4 u = *ga;
            uint2 o; o.x = pkh(decf(u.x), decf(u.y)); o.y = pkh(decf(u.z), decf(u.w));
            *(uint2*)(Ts + row*LP + qc*4) = o;
        }
    }
    dma_w(g1T, Ws, wv, lane);
    __syncthreads();                                   // bar1

    f32x4 acc[8];
    zero_acc8(acc);
    gemm64(Ts, Ws, acc, wv, lq, quad);                 // agg @ G1
    __syncthreads();                                   // bar2
    dma_w(g2T, Ws, wv, lane);
    #pragma unroll
    for (int ct = 0; ct < 8; ct++)
        #pragma unroll
        for (int rg = 0; rg < 4; rg++){
            int c = ct*16 + lq;
            Ts[(wv*16 + quad*4 + rg)*LP + c] = (_Float16)fmaxf(acc[ct][rg] + c1s[c], 0.f);
        }
    __syncthreads();                                   // bar3

    zero_acc8(acc);
    gemm64(Ts, Ws, acc, wv, lq, quad);                 // P @ G2

    #pragma unroll
    for (int ct = 0; ct < 8; ct++)
        #pragma unroll
        for (int rg = 0; rg < 4; rg++){
            int c = ct*16 + lq;
            outf[(size_t)(node0 + wv*16 + quad*4 + rg)*HID + c] = acc[ct][rg] + c2s[c];
        }
}

extern "C" void kernel_launch(void* const* d_in, const int* in_sizes, int n_in,
                              void* d_out, int out_size, void* d_ws, size_t ws_size,
                              hipStream_t stream){
    const float* x   = (const float*)d_in[0];
    const float* pos = (const float*)d_in[1];
    const int*   ei  = (const int*)d_in[2];
    const float* W[16];
    for (int i = 0; i < 16; i++) W[i] = (const float*)d_in[3 + i];
    // per layer l: lw1=W[8l+0] lb1=+1 lw2=+2 lb2=+3 gw1=+4 gb1=+5 gw2=+6 gb2=+7

    uint8_t* p = (uint8_t*)d_ws;
    _Float16* wT[10];
    for (int i = 0; i < 10; i++) wT[i] = (_Float16*)(p + (size_t)i * 32768);
    size_t off = 10 * 32768;
    _Float16* Ah  = (_Float16*)(p + off); off += (size_t)NN * HID * 2;
    _Float16* Bh0 = (_Float16*)(p + off); off += (size_t)NN * HID * 2;
    _Float16* Bh1 = (_Float16*)(p + off); off += (size_t)NN * HID * 2;
    uint32_t* agg = (uint32_t*)(p + off); off += (size_t)NN * HID * 4;
    uint32_t* cnt = (uint32_t*)(p + off); off += (size_t)NN * 4;
    uint32_t* cur = (uint32_t*)(p + off); off += (size_t)NN * 4;
    uint32_t* bsum = (uint32_t*)(p + off); off += 256 * 4;
    uint32_t* bofs = (uint32_t*)(p + off); off += 256 * 4;
    float* c1p = (float*)(p + off); off += 256 * 4;
    uint2* sedge = (uint2*)(p + off); off += (size_t)E2 * 8;
    (void)ws_size; (void)in_sizes; (void)n_in; (void)out_size; (void)bofs;

    // weight transpose slots per layer: W1a^T, W1b^T, W2^T, G1^T, G2^T
    WT wt;
    for (int l = 0; l < 2; l++){
        wt.s[5*l + 0] = W[8*l + 0];
        wt.s[5*l + 1] = W[8*l + 0] + 128*128;
        wt.s[5*l + 2] = W[8*l + 2];
        wt.s[5*l + 3] = W[8*l + 4];
        wt.s[5*l + 4] = W[8*l + 6];
        for (int j = 0; j < 5; j++) wt.d[5*l + j] = wT[5*l + j];
    }
    k_prep<<<898, 256, 0, stream>>>(wt, cnt, W[3], W[4], W[5], W[11], W[12], W[13], c1p);

    // fused: layer-0 A/B GEMMs (blocks 0-1023) + edge histogram (1024-5119)
    k_histab3<<<1024 + NE/256, 256, 0, stream>>>(ei, cnt, x, pos, wT[0], wT[1], wT[6],
                                                 W[1], Ah, Bh0, Bh1, agg);
    k_scan1<<<256, 256, 0, stream>>>(cnt, bsum);
    k_scan23<<<256, 256, 0, stream>>>(cnt, bsum, cur);
    k_scatter<<<(E2 + 255)/256, 256, 0, stream>>>(ei, cur, sedge);

    k_edge<<<E2/128, 256, 0, stream>>>(sedge, Ah, Bh0, wT[2], agg);
    k_gnn_ab<<<NN/64, 256, 0, stream>>>(agg, wT[3], wT[4], c1p, W[7],
                                        wT[5], Bh1, W[9], Ah);
    k_edge<<<E2/128, 256, 0, stream>>>(sedge, Ah, Bh1, wT[7], agg);
    k_gnn<<<NN/64, 256, 0, stream>>>(agg, wT[8], wT[9], c1p + 128, W[15],
                                     (float*)d_out);
}

// Round 8
// 450.010 us; speedup vs baseline: 1.1791x; 1.0052x over previous
//
#include <hip/hip_runtime.h>
#include <hip/hip_bf16.h>
#include <stdint.h>

#define NN 65536
#define NE 1048576
#define E2 (NE + NN)      // edges + self loops = 1,114,112 = 8704*128
#define HID 128
#define LP 136            // padded LDS row pitch (fp16 elems) for node-kernel A tiles
#define RMAX 13           // max runs in LDS run-table (overflow -> global atomics)
#define TP 129            // run-table stride in words
#define TABW 1680         // ceil(RMAX*TP/4)*4 words
#define ENC_NEG 0x007FFFFFu   // encf(-inf)

typedef _Float16 h8v __attribute__((ext_vector_type(8)));
typedef __fp16 fp16x2 __attribute__((ext_vector_type(2)));
typedef __attribute__((ext_vector_type(4))) float f32x4;

__device__ __forceinline__ uint32_t pkh(float a, float b){
    union { fp16x2 h; uint32_t u; } v;
    v.h = __builtin_amdgcn_cvt_pkrtz(a, b);
    return v.u;
}
// monotone float->uint encoding for unsigned atomicMax (branchless)
__device__ __forceinline__ uint32_t encf(float x){
    union { float f; uint32_t u; } v; v.f = x;
    return v.u ^ (uint32_t)(((int32_t)v.u >> 31) | 0x80000000);
}
__device__ __forceinline__ float decf(uint32_t u){
    union { uint32_t u; float f; } v;
    v.u = u ^ (uint32_t)(~((int32_t)u >> 31) | 0x80000000);
    return v.f;
}

// direct global->LDS DMA, 16B per lane (dest = wave-uniform base + lane*16)
__device__ __forceinline__ void gl_lds16(const _Float16* g, _Float16* l){
    __builtin_amdgcn_global_load_lds(
        (const __attribute__((address_space(1))) uint32_t*)g,
        (__attribute__((address_space(3))) uint32_t*)l, 16, 0, 0);
}

// stage a 128x128 fp16 weight into LDS via DMA (4-wave version, k_edge):
// linear dest, inverse-XOR-swizzled per-lane global source.
__device__ __forceinline__ void dma_w(const _Float16* __restrict__ wT, _Float16* Ws,
                                      int wv, int lane){
    #pragma unroll
    for (int rnd = 0; rnd < 8; rnd++){
        int g = rnd*256 + wv*64 + lane;              // 16B chunk id 0..2047
        int r = g >> 4, kc = g & 15;
        gl_lds16(wT + r*HID + ((kc ^ (r & 15)) << 3),
                 Ws + rnd*2048 + wv*512);
    }
}
// 8-wave version (512-thread node kernels): same layout, 4 rounds.
__device__ __forceinline__ void dma_w8(const _Float16* __restrict__ wT, _Float16* Ws,
                                       int wv, int lane){
    #pragma unroll
    for (int rnd = 0; rnd < 4; rnd++){
        int g = rnd*512 + wv*64 + lane;              // 16B chunk id 0..2047
        int r = g >> 4, kc = g & 15;
        gl_lds16(wT + r*HID + ((kc ^ (r & 15)) << 3),
                 Ws + rnd*4096 + wv*512);
    }
}

// per-wave 16x128x128 fp16 GEMM slice: A rows wv*16..+15 from padded LDS tile,
// B from swizzled Ws. acc[ct] covers col ct*16+lq, rows quad*4+rg.
// R5 lesson: weights must be LDS-resident, not direct-global.
__device__ __forceinline__ void gemm_w(const _Float16* Ts, const _Float16* Ws,
                                       f32x4 (&acc)[8], int wv, int lq, int quad){
    #pragma unroll
    for (int k0 = 0; k0 < 128; k0 += 32){
        h8v af = *(const h8v*)(Ts + (wv*16 + lq)*LP + k0 + quad*8);
        const int kcb = k0 >> 3;
        #pragma unroll
        for (int ct = 0; ct < 8; ct++){
            h8v b = *(const h8v*)(Ws + (ct*16 + lq)*128 + (((kcb + quad) ^ lq) << 3));
            acc[ct] = __builtin_amdgcn_mfma_f32_16x16x32_f16(af, b, acc[ct], 0, 0, 0);
        }
    }
}

__device__ __forceinline__ void zero_acc8(f32x4 (&acc)[8]){
    #pragma unroll
    for (int b = 0; b < 8; b++) acc[b] = (f32x4){0.f, 0.f, 0.f, 0.f};
}

__device__ __forceinline__ void zero_acc(f32x4 (&acc)[2][8]){
    #pragma unroll
    for (int a = 0; a < 2; a++)
        #pragma unroll
        for (int b = 0; b < 8; b++)
            acc[a][b] = (f32x4){0.f, 0.f, 0.f, 0.f};
}

// ---------------- prep: weight transposes + cnt init + folded bias ----------------
struct WT { const float* s[10]; _Float16* d[10]; };
__global__ void k_prep(WT w, uint32_t* cnt,
                       const float* lb2_0, const float* gw1_0, const float* gb1_0,
                       const float* lb2_1, const float* gw1_1, const float* gb1_1,
                       float* c1p){
    int b = blockIdx.x;
    if (b < 640){
        int m = b >> 6;
        int t = (b & 63) * 256 + threadIdx.x;
        int n = t >> 7, k = t & 127;
        w.d[m][n*128 + k] = (_Float16)w.s[m][k*128 + n];
    } else if (b < 896){
        cnt[(b - 640)*256 + threadIdx.x] = 1u;        // self-loop pre-counted
    } else {
        // c1'[l][j] = gb1[j] + sum_k lb2[k]*gw1[k][j]   (folds b2 out of k_edge)
        int l = b - 896;
        int j = threadIdx.x;
        if (j < 128){
            const float* lb2 = l ? lb2_1 : lb2_0;
            const float* gw1 = l ? gw1_1 : gw1_0;
            float s = (l ? gb1_1 : gb1_0)[j];
            for (int k = 0; k < 128; k++) s += lb2[k] * gw1[k*128 + j];
            c1p[l*128 + j] = s;
        }
    }
}

// ---------------- fused hist + ab3 (512 threads, 128-row tiles) ----------------
// blocks 0..511: ab3 (single-acc ordering: B1, then B0 carried into A-accum);
// blocks 512..2559: edge histogram (512 edges/block).
// LDS: Ts 34.8K + Ws 32.8K ~ 68.1K -> 2 blocks/CU = 16 waves/CU; grid 512 = one
// full generation (no tail). launch_bounds(512,4) -> 128 unified regs (32 AGPR).
__launch_bounds__(512, 4)
__global__ void k_histab3(const int* __restrict__ ei, uint32_t* __restrict__ cnt,
                          const float* __restrict__ x, const float* __restrict__ pos,
                          const _Float16* __restrict__ w1aT0, const _Float16* __restrict__ w1bT0,
                          const _Float16* __restrict__ w1bT1, const float* __restrict__ lb1_0,
                          _Float16* __restrict__ Ah, _Float16* __restrict__ Bh0,
                          _Float16* __restrict__ Bh1, uint32_t* __restrict__ agg){
    __shared__ _Float16 Ts[128*LP];
    __shared__ _Float16 Ws[128*128];
    __shared__ float b1s[128];
    const int tid = threadIdx.x;

    if (blockIdx.x >= 512){                            // ---- histogram part ----
        int e = (blockIdx.x - 512) * 512 + tid;
        atomicAdd(&cnt[ei[NE + e]], 1u);
        return;
    }

    const int node0 = blockIdx.x * 128;
    const int wv = tid >> 6, lane = tid & 63, lq = lane & 15, quad = lane >> 4;
    if (tid < 128) b1s[tid] = lb1_0[tid];

    {   // init agg for this node range (128 rows = 16384 words)
        uint4* ap = (uint4*)(agg + (size_t)node0 * HID);
        uint4 v = make_uint4(ENC_NEG, ENC_NEG, ENC_NEG, ENC_NEG);
        #pragma unroll
        for (int i = 0; i < 8; i++) ap[tid + i*512] = v;
    }
    // stage pos -> Ts (chunk-linear coalesced; 2048 16B-chunks / 512 thr = 4 each)
    #pragma unroll
    for (int i = 0; i < 4; i++){
        int chunk = tid + i*512;
        int row = chunk >> 4, qc = chunk & 15;
        const float4* src = (const float4*)(pos + (size_t)(node0 + row)*HID + qc*8);
        float4 f0 = src[0], f1 = src[1];
        uint4 o; o.x = pkh(f0.x, f0.y); o.y = pkh(f0.z, f0.w);
        o.z = pkh(f1.x, f1.y); o.w = pkh(f1.z, f1.w);
        *(uint4*)(Ts + row*LP + qc*8) = o;
    }
    dma_w8(w1bT1, Ws, wv, lane);
    __syncthreads();                                   // bar1: Ts+Ws ready

    f32x4 acc[8];
    zero_acc8(acc);
    gemm_w(Ts, Ws, acc, wv, lq, quad);                 // pos @ W1b1
    __syncthreads();                                   // bar2: Ws readers done
    dma_w8(w1bT0, Ws, wv, lane);
    #pragma unroll
    for (int ct = 0; ct < 8; ct++)
        #pragma unroll
        for (int rg = 0; rg < 4; rg++)
            Bh1[(size_t)(node0 + wv*16 + quad*4 + rg)*HID + ct*16 + lq]
                = (_Float16)acc[ct][rg];
    __syncthreads();                                   // bar3: Ws=W1b0 ready

    zero_acc8(acc);
    gemm_w(Ts, Ws, acc, wv, lq, quad);                 // acc = pos @ W1b0 (kept)
    __syncthreads();                                   // bar4: Ts+Ws readers done

    #pragma unroll
    for (int i = 0; i < 4; i++){                       // stage x -> Ts
        int chunk = tid + i*512;
        int row = chunk >> 4, qc = chunk & 15;
        const float4* src = (const float4*)(x + (size_t)(node0 + row)*HID + qc*8);
        float4 f0 = src[0], f1 = src[1];
        uint4 o; o.x = pkh(f0.x, f0.y); o.y = pkh(f0.z, f0.w);
        o.z = pkh(f1.x, f1.y); o.w = pkh(f1.z, f1.w);
        *(uint4*)(Ts + row*LP + qc*8) = o;
    }
    dma_w8(w1aT0, Ws, wv, lane);
    #pragma unroll
    for (int ct = 0; ct < 8; ct++)                     // store B0 (acc kept live)
        #pragma unroll
        for (int rg = 0; rg < 4; rg++)
            Bh0[(size_t)(node0 + wv*16 + quad*4 + rg)*HID + ct*16 + lq]
                = (_Float16)acc[ct][rg];
    __syncthreads();                                   // bar5: Ts=x + Ws=W1a0 ready

    gemm_w(Ts, Ws, acc, wv, lq, quad);                 // acc += x @ W1a0

    #pragma unroll
    for (int ct = 0; ct < 8; ct++)
        #pragma unroll
        for (int rg = 0; rg < 4; rg++){
            int c = ct*16 + lq;
            Ah[(size_t)(node0 + wv*16 + quad*4 + rg)*HID + c]
                = (_Float16)(acc[ct][rg] + b1s[c]);
        }
}

__global__ void k_scan1(const uint32_t* __restrict__ cnt, uint32_t* __restrict__ bsum){
    __shared__ uint32_t ps[256];
    int t = threadIdx.x;
    ps[t] = cnt[blockIdx.x*256 + t]; __syncthreads();
    for (int off = 128; off > 0; off >>= 1){
        if (t < off) ps[t] += ps[t + off];
        __syncthreads();
    }
    if (t == 0) bsum[blockIdx.x] = ps[0];
}
// fused scan2+scan3: each block re-derives its bsum-prefix offset in LDS
__global__ void k_scan23(const uint32_t* __restrict__ cnt, const uint32_t* __restrict__ bsum,
                         uint32_t* __restrict__ cur){
    __shared__ uint32_t ps[256];
    __shared__ uint32_t bs[256];
    int t = threadIdx.x, b = blockIdx.x, i = b*256 + t;
    uint32_t bb = bsum[b];
    bs[t] = bsum[t];
    uint32_t v = cnt[i];
    ps[t] = v; __syncthreads();
    for (int off = 1; off < 256; off <<= 1){
        uint32_t u = (t >= off) ? ps[t - off] : 0u;
        uint32_t w = (t >= off) ? bs[t - off] : 0u;
        __syncthreads();
        ps[t] += u; bs[t] += w;
        __syncthreads();
    }
    cur[i] = (bs[b] - bb) + ps[t] - v;
}
__global__ void k_scatter(const int* __restrict__ ei, uint32_t* cur,
                          uint2* __restrict__ sedge){
    int e = blockIdx.x * 256 + threadIdx.x;
    if (e >= E2) return;
    uint32_t s, d;
    if (e < NE){ s = (uint32_t)ei[e]; d = (uint32_t)ei[NE + e]; }
    else { s = d = (uint32_t)(e - NE); }
    uint32_t p = atomicAdd(&cur[d], 1u);
    sedge[p] = make_uint2(s, d);
}

// -------- edge kernel: agg[dst] = max over edges of relu(A[src]-B[dst]) @ W2 --------
// R4 structure (proven): 2 barriers, DMA-staged W2, per-lane edge loads, own-region
// run-table; 4 blocks/CU (LDS 40448, 128 unified regs).
__launch_bounds__(256, 4)
__global__ void k_edge(const uint2* __restrict__ sedge,
                       const _Float16* __restrict__ Ah, const _Float16* __restrict__ Bh,
                       const _Float16* __restrict__ w2T,
                       uint32_t* __restrict__ agg){
    __shared__ _Float16 Ws[128*128];                 // 32768 B, swizzled W2
    __shared__ __align__(16) uint32_t tab[TABW];     // 6720 B run-table (own region)
    __shared__ int ds_s[128];
    __shared__ unsigned long long masks_s[2];
    __shared__ int run_dst_s[RMAX];
    const int tid = threadIdx.x;
    const int bid = blockIdx.x;
    const int lb  = (bid & 7) * (E2/128/8) + (bid >> 3);   // XCD swizzle
    const int e0 = lb * 128;
    const int wv = tid >> 6, lane = tid & 63, lq = lane & 15, quad = lane >> 4;
    const int r0 = wv*32 + lq, r1 = r0 + 16;

    // ---- edge loads first (oldest in vmem FIFO -> cheap counted wait) ----
    const uint2 ea = sedge[e0 + r0];
    const uint2 eb = sedge[e0 + r1];
    int d_cur = 0;
    if (tid < 128) d_cur = (int)sedge[e0 + tid].y;

    // ---- W2 global->LDS DMA: linear dest, inverse-swizzled source ----
    dma_w(w2T, Ws, wv, lane);

    // gathers: issue ASAP; drain at barrier1 under DMA + LDS bookkeeping
    const _Float16* a0p = Ah + (size_t)ea.x*HID + quad*8;
    const _Float16* a1p = Ah + (size_t)eb.x*HID + quad*8;
    const _Float16* b0p = Bh + (size_t)ea.y*HID + quad*8;
    const _Float16* b1p = Bh + (size_t)eb.y*HID + quad*8;
    h8v A0[4], A1[4], B0[4], B1[4];
    #pragma unroll
    for (int i = 0; i < 4; i++){
        A0[i] = *(const h8v*)(a0p + 32*i);
        A1[i] = *(const h8v*)(a1p + 32*i);
        B0[i] = *(const h8v*)(b0p + 32*i);
        B1[i] = *(const h8v*)(b1p + 32*i);
    }

    // boundary flags: d_prev via in-wave shuffles (no extra global loads).
    // lanes with (r1==63) hold sedge[e0+63] in eb -> shfl lane 15 serves tid 64.
    bool flag = false;
    if (tid < 128){
        ds_s[tid] = d_cur;
        int d_up  = __shfl_up(d_cur, 1);
        int d_b63 = __shfl((int)eb.y, 15);
        if (tid & 63) flag = (d_cur != d_up);
        else          flag = (tid == 0) ? true : (d_cur != d_b63);
        unsigned long long m = __ballot(flag);
        if ((tid & 63) == 0) masks_s[tid >> 6] = m;
    }
    {   // init run-table (TABW/4 = 420 uint4)
        uint4* t4 = (uint4*)tab;
        const uint4 vneg = make_uint4(ENC_NEG, ENC_NEG, ENC_NEG, ENC_NEG);
        #pragma unroll
        for (int i = 0; i < 2; i++){
            int idx = tid + i*256;
            if (idx < TABW/4) t4[idx] = vneg;
        }
    }
    __syncthreads();                            // barrier1: Ws/ds_s/masks/tab ready

    const unsigned long long m0 = masks_s[0], m1 = masks_s[1];
    const int c0 = __popcll(m0);
    const int nruns = c0 + __popcll(m1);

    // boundary threads record their run's dst (read post-barrier2 only)
    if (flag){
        int r;
        if (tid < 64) r = __popcll(m0 & ((2ull << tid) - 1)) - 1;
        else          r = c0 + __popcll(m1 & ((2ull << (tid-64)) - 1)) - 1;
        if (r < RMAX) run_dst_s[r] = d_cur;
    }

    f32x4 acc[2][8];
    zero_acc(acc);

    const h8v zero8 = (h8v)(_Float16)0;
    #pragma unroll
    for (int i = 0; i < 4; i++){
        h8v a0 = __builtin_elementwise_max(A0[i] - B0[i], zero8);
        h8v a1 = __builtin_elementwise_max(A1[i] - B1[i], zero8);
        const int kcb = i*4;
        #pragma unroll
        for (int ct = 0; ct < 8; ct++){
            h8v b = *(const h8v*)(Ws + (ct*16 + lq)*128 + (((kcb + quad) ^ lq) << 3));
            acc[0][ct] = __builtin_amdgcn_mfma_f32_16x16x32_f16(a0, b, acc[0][ct], 0, 0, 0);
            acc[1][ct] = __builtin_amdgcn_mfma_f32_16x16x32_f16(a1, b, acc[1][ct], 0, 0, 0);
        }
    }

    // flush acc -> run-table (tab does not alias Ws: no barrier needed)
    #pragma unroll
    for (int rt = 0; rt < 2; rt++){
        const int rb = wv*32 + rt*16 + quad*4;
        int rid[4];
        #pragma unroll
        for (int i = 0; i < 4; i++){
            int r = rb + i;
            if (r < 64) rid[i] = __popcll(m0 & ((2ull << r) - 1)) - 1;
            else        rid[i] = c0 + __popcll(m1 & ((2ull << (r-64)) - 1)) - 1;
        }
        const bool b01 = rid[1] != rid[0];
        const bool b12 = rid[2] != rid[1];
        const bool b23 = rid[3] != rid[2];
        #pragma unroll
        for (int ct = 0; ct < 8; ct++){
            const int c = ct*16 + lq;
            float v0 = acc[rt][ct][0], v1 = acc[rt][ct][1];
            float v2 = acc[rt][ct][2], v3 = acc[rt][ct][3];
            #define FLUSH(ID, R, V) do{ uint32_t ev = encf(V); \
                if (__builtin_expect((ID) < RMAX, 1)) atomicMax(&tab[(ID)*TP + c], ev); \
                else atomicMax(&agg[(size_t)ds_s[R]*HID + c], ev); }while(0)
            if (b01) FLUSH(rid[0], rb+0, v0); else v1 = fmaxf(v1, v0);
            if (b12) FLUSH(rid[1], rb+1, v1); else v2 = fmaxf(v2, v1);
            if (b23) FLUSH(rid[2], rb+2, v2); else v3 = fmaxf(v3, v2);
            FLUSH(rid[3], rb+3, v3);
            #undef FLUSH
        }
    }
    __syncthreads();                            // barrier2: table + run_dst complete

    {   // flush: boundary runs -> atomicMax; interior runs sole-writer -> plain store
        const int c = tid & 127;
        const int ntab = nruns < RMAX ? nruns : RMAX;
        for (int r = tid >> 7; r < ntab; r += 2){
            uint32_t v = tab[r*TP + c];
            uint32_t* dst = &agg[(size_t)run_dst_s[r]*HID + c];
            if (r == 0 || r == nruns-1 || nruns > RMAX) atomicMax(dst, v);
            else *dst = v;
        }
    }
}

// -------- fused layer-0 global nn + layer-1 A (512 thr, 128-row tiles) --------
// out0 = relu(agg@G1 + c1')@G2 + c2 ; A1 = out0@W1a1 + B1 + b1_1 ; agg re-init.
__launch_bounds__(512, 4)
__global__ void k_gnn_ab(uint32_t* __restrict__ agg,
                         const _Float16* __restrict__ g1T, const _Float16* __restrict__ g2T,
                         const float* __restrict__ c1p, const float* __restrict__ gb2,
                         const _Float16* __restrict__ w1aT1, const _Float16* __restrict__ Bh1,
                         const float* __restrict__ lb1_1,
                         _Float16* __restrict__ Ah){
    __shared__ _Float16 Ts[128*LP];
    __shared__ _Float16 Ws[128*128];
    __shared__ float c1s[128];
    __shared__ float c2s[128];
    __shared__ float b1s[128];
    const int tid = threadIdx.x;
    const int node0 = blockIdx.x * 128;
    const int wv = tid >> 6, lane = tid & 63, lq = lane & 15, quad = lane >> 4;
    if (tid < 128){ c1s[tid] = c1p[tid]; c2s[tid] = gb2[tid]; b1s[tid] = lb1_1[tid]; }

    {   // decode agg -> Ts (+re-init), chunk-linear coalesced (4096 uint4 / 512)
        const uint4 vneg = make_uint4(ENC_NEG, ENC_NEG, ENC_NEG, ENC_NEG);
        #pragma unroll
        for (int i = 0; i < 8; i++){
            int chunk = tid + i*512;
            int row = chunk >> 5, qc = chunk & 31;
            uint4* ga = (uint4*)(agg + (size_t)(node0 + row)*HID + qc*4);
            uint4 u = *ga; *ga = vneg;
            uint2 o; o.x = pkh(decf(u.x), decf(u.y)); o.y = pkh(decf(u.z), decf(u.w));
            *(uint2*)(Ts + row*LP + qc*4) = o;
        }
    }
    dma_w8(g1T, Ws, wv, lane);
    __syncthreads();                                   // bar1

    f32x4 acc[8];
    zero_acc8(acc);
    gemm_w(Ts, Ws, acc, wv, lq, quad);                 // agg @ G1
    __syncthreads();                                   // bar2: Ts+Ws readers done
    dma_w8(g2T, Ws, wv, lane);
    #pragma unroll
    for (int ct = 0; ct < 8; ct++)
        #pragma unroll
        for (int rg = 0; rg < 4; rg++){
            int c = ct*16 + lq;
            Ts[(wv*16 + quad*4 + rg)*LP + c] = (_Float16)fmaxf(acc[ct][rg] + c1s[c], 0.f);
        }
    __syncthreads();                                   // bar3

    zero_acc8(acc);
    gemm_w(Ts, Ws, acc, wv, lq, quad);                 // P @ G2
    __syncthreads();                                   // bar4
    dma_w8(w1aT1, Ws, wv, lane);
    #pragma unroll
    for (int ct = 0; ct < 8; ct++)
        #pragma unroll
        for (int rg = 0; rg < 4; rg++){
            int c = ct*16 + lq;
            Ts[(wv*16 + quad*4 + rg)*LP + c] = (_Float16)(acc[ct][rg] + c2s[c]);
        }
    __syncthreads();                                   // bar5

    // prefetch Bh1 residual into regs (latency hidden under GEMM3)
    _Float16 bres[8][4];
    #pragma unroll
    for (int ct = 0; ct < 8; ct++)
        #pragma unroll
        for (int rg = 0; rg < 4; rg++)
            bres[ct][rg] = Bh1[(size_t)(node0 + wv*16 + quad*4 + rg)*HID + ct*16 + lq];

    zero_acc8(acc);
    gemm_w(Ts, Ws, acc, wv, lq, quad);                 // out0 @ W1a1

    #pragma unroll
    for (int ct = 0; ct < 8; ct++)
        #pragma unroll
        for (int rg = 0; rg < 4; rg++){
            int c = ct*16 + lq;
            float v = acc[ct][rg] + (float)bres[ct][rg] + b1s[c];
            Ah[(size_t)(node0 + wv*16 + quad*4 + rg)*HID + c] = (_Float16)v;
        }
}

// -------- final global nn (512 thr, 128-row tiles): relu(agg@G1+c1')@G2 + c2 ----
__launch_bounds__(512, 4)
__global__ void k_gnn(const uint32_t* __restrict__ agg,
                      const _Float16* __restrict__ g1T, const _Float16* __restrict__ g2T,
                      const float* __restrict__ c1p, const float* __restrict__ gb2,
                      float* __restrict__ outf){
    __shared__ _Float16 Ts[128*LP];
    __shared__ _Float16 Ws[128*128];
    __shared__ float c1s[128];
    __shared__ float c2s[128];
    const int tid = threadIdx.x;
    const int node0 = blockIdx.x * 128;
    const int wv = tid >> 6, lane = tid & 63, lq = lane & 15, quad = lane >> 4;
    if (tid < 128){ c1s[tid] = c1p[tid]; c2s[tid] = gb2[tid]; }

    {   // decode agg -> Ts, chunk-linear coalesced
        #pragma unroll
        for (int i = 0; i < 8; i++){
            int chunk = tid + i*512;
            int row = chunk >> 5, qc = chunk & 31;
            const uint4* ga = (const uint4*)(agg + (size_t)(node0 + row)*HID + qc*4);
            uint4 u = *ga;
            uint2 o; o.x = pkh(decf(u.x), decf(u.y)); o.y = pkh(decf(u.z), decf(u.w));
            *(uint2*)(Ts + row*LP + qc*4) = o;
        }
    }
    dma_w8(g1T, Ws, wv, lane);
    __syncthreads();                                   // bar1

    f32x4 acc[8];
    zero_acc8(acc);
    gemm_w(Ts, Ws, acc, wv, lq, quad);                 // agg @ G1
    __syncthreads();                                   // bar2
    dma_w8(g2T, Ws, wv, lane);
    #pragma unroll
    for (int ct = 0; ct < 8; ct++)
        #pragma unroll
        for (int rg = 0; rg < 4; rg++){
            int c = ct*16 + lq;
            Ts[(wv*16 + quad*4 + rg)*LP + c] = (_Float16)fmaxf(acc[ct][rg] + c1s[c], 0.f);
        }
    __syncthreads();                                   // bar3

    zero_acc8(acc);
    gemm_w(Ts, Ws, acc, wv, lq, quad);                 // P @ G2

    #pragma unroll
    for (int ct = 0; ct < 8; ct++)
        #pragma unroll
        for (int rg = 0; rg < 4; rg++){
            int c = ct*16 + lq;
            outf[(size_t)(node0 + wv*16 + quad*4 + rg)*HID + c] = acc[ct][rg] + c2s[c];
        }
}

extern "C" void kernel_launch(void* const* d_in, const int* in_sizes, int n_in,
                              void* d_out, int out_size, void* d_ws, size_t ws_size,
                              hipStream_t stream){
    const float* x   = (const float*)d_in[0];
    const float* pos = (const float*)d_in[1];
    const int*   ei  = (const int*)d_in[2];
    const float* W[16];
    for (int i = 0; i < 16; i++) W[i] = (const float*)d_in[3 + i];
    // per layer l: lw1=W[8l+0] lb1=+1 lw2=+2 lb2=+3 gw1=+4 gb1=+5 gw2=+6 gb2=+7

    uint8_t* p = (uint8_t*)d_ws;
    _Float16* wT[10];
    for (int i = 0; i < 10; i++) wT[i] = (_Float16*)(p + (size_t)i * 32768);
    size_t off = 10 * 32768;
    _Float16* Ah  = (_Float16*)(p + off); off += (size_t)NN * HID * 2;
    _Float16* Bh0 = (_Float16*)(p + off); off += (size_t)NN * HID * 2;
    _Float16* Bh1 = (_Float16*)(p + off); off += (size_t)NN * HID * 2;
    uint32_t* agg = (uint32_t*)(p + off); off += (size_t)NN * HID * 4;
    uint32_t* cnt = (uint32_t*)(p + off); off += (size_t)NN * 4;
    uint32_t* cur = (uint32_t*)(p + off); off += (size_t)NN * 4;
    uint32_t* bsum = (uint32_t*)(p + off); off += 256 * 4;
    uint32_t* bofs = (uint32_t*)(p + off); off += 256 * 4;
    float* c1p = (float*)(p + off); off += 256 * 4;
    uint2* sedge = (uint2*)(p + off); off += (size_t)E2 * 8;
    (void)ws_size; (void)in_sizes; (void)n_in; (void)out_size; (void)bofs;

    // weight transpose slots per layer: W1a^T, W1b^T, W2^T, G1^T, G2^T
    WT wt;
    for (int l = 0; l < 2; l++){
        wt.s[5*l + 0] = W[8*l + 0];
        wt.s[5*l + 1] = W[8*l + 0] + 128*128;
        wt.s[5*l + 2] = W[8*l + 2];
        wt.s[5*l + 3] = W[8*l + 4];
        wt.s[5*l + 4] = W[8*l + 6];
        for (int j = 0; j < 5; j++) wt.d[5*l + j] = wT[5*l + j];
    }
    k_prep<<<898, 256, 0, stream>>>(wt, cnt, W[3], W[4], W[5], W[11], W[12], W[13], c1p);

    // fused: layer-0 A/B GEMMs (blocks 0-511) + edge histogram (512-2559)
    k_histab3<<<512 + NE/512, 512, 0, stream>>>(ei, cnt, x, pos, wT[0], wT[1], wT[6],
                                                W[1], Ah, Bh0, Bh1, agg);
    k_scan1<<<256, 256, 0, stream>>>(cnt, bsum);
    k_scan23<<<256, 256, 0, stream>>>(cnt, bsum, cur);
    k_scatter<<<(E2 + 255)/256, 256, 0, stream>>>(ei, cur, sedge);

    k_edge<<<E2/128, 256, 0, stream>>>(sedge, Ah, Bh0, wT[2], agg);
    k_gnn_ab<<<NN/128, 512, 0, stream>>>(agg, wT[3], wT[4], c1p, W[7],
                                         wT[5], Bh1, W[9], Ah);
    k_edge<<<E2/128, 256, 0, stream>>>(sedge, Ah, Bh1, wT[7], agg);
    k_gnn<<<NN/128, 512, 0, stream>>>(agg, wT[8], wT[9], c1p + 128, W[15],
                                      (float*)d_out);
}